// Round 9
// baseline (746.119 us; speedup 1.0000x reference)
//
#include <hip/hip_runtime.h>
#include <hip/hip_bf16.h>
#include <cstdint>
#include <cstddef>

#define NEG_SLOPE 0.2f

typedef float f4v __attribute__((ext_vector_type(4)));
typedef short short8 __attribute__((ext_vector_type(8)));
typedef float f32x4 __attribute__((ext_vector_type(4)));

// fp32 -> 3x bf16 (h,m exact chops; l = RN of remainder). h+m+l = v to
// ~2^-24 rel. GEMM keeps products {hh,hm,mh,hl,mm,lh} -> fp32-grade result.
__device__ __forceinline__ void cvt3(float v, short& h, short& m, short& l) {
  unsigned u = __builtin_bit_cast(unsigned, v);
  h = (short)(u >> 16);
  float hf = __builtin_bit_cast(float, u & 0xFFFF0000u);
  float r1 = v - hf;
  unsigned u1 = __builtin_bit_cast(unsigned, r1);
  m = (short)(u1 >> 16);
  float mf = __builtin_bit_cast(float, u1 & 0xFFFF0000u);
  l = __builtin_bit_cast(short, __float2bfloat16(r1 - mf));
}

// ---------- CSR build ----------

__global__ __launch_bounds__(256) void fill_ones_kernel(int* __restrict__ p, int n) {
  int i = blockIdx.x * 256 + threadIdx.x;
  if (i < n) p[i] = 1;  // self-loop contributes degree 1
}

__global__ __launch_bounds__(256) void degree_count_kernel(
    const int* __restrict__ ei, int E, int* __restrict__ deg) {
  int e = blockIdx.x * 256 + threadIdx.x;
  if (e < E) atomicAdd(&deg[ei[E + e]], 1);
}

__global__ __launch_bounds__(1024) void scan1_kernel(
    const int* __restrict__ deg, int n, int* __restrict__ incl,
    int* __restrict__ blocksums) {
  __shared__ int sm[1024];
  int t = threadIdx.x;
  int i = blockIdx.x * 1024 + t;
  sm[t] = (i < n) ? deg[i] : 0;
  __syncthreads();
  #pragma unroll
  for (int o = 1; o < 1024; o <<= 1) {
    int a = (t >= o) ? sm[t - o] : 0;
    __syncthreads();
    sm[t] += a;
    __syncthreads();
  }
  if (i < n) incl[i] = sm[t];
  if (t == 1023) blocksums[blockIdx.x] = sm[t];
}

__global__ __launch_bounds__(1024) void scan2_kernel(int* __restrict__ bs, int nb) {
  __shared__ int sm[1024];
  int t = threadIdx.x;
  sm[t] = (t < nb) ? bs[t] : 0;
  __syncthreads();
  #pragma unroll
  for (int o = 1; o < 1024; o <<= 1) {
    int a = (t >= o) ? sm[t - o] : 0;
    __syncthreads();
    sm[t] += a;
    __syncthreads();
  }
  if (t < nb) bs[t] = sm[t];
}

__global__ __launch_bounds__(1024) void scan3_kernel(
    const int* __restrict__ incl, const int* __restrict__ deg,
    const int* __restrict__ bs, int n, int* __restrict__ rowcur) {
  int i = blockIdx.x * 1024 + threadIdx.x;
  if (i >= n) return;
  int off = (blockIdx.x > 0) ? bs[blockIdx.x - 1] : 0;
  rowcur[i] = incl[i] - deg[i] + off;
}

__global__ __launch_bounds__(256) void scatter_kernel(
    const int* __restrict__ ei, int E, int ET, int* __restrict__ rowcur,
    int* __restrict__ csr_src) {
  int e = blockIdx.x * 256 + threadIdx.x;
  if (e >= ET) return;
  int s, d;
  if (e < E) { s = ei[e]; d = ei[E + e]; }
  else       { s = e - E; d = s; }
  int pos = atomicAdd(&rowcur[d], 1);
  csr_src[pos] = s;
}

// ---------- W -> MFMA B-fragment layout (triple bf16 planes) ----------
struct PrepArgs {
  const float* w[8];
  short* o[8];
  int fout[8];
  int cum[9];
};

__global__ __launch_bounds__(256) void prep_w_kernel(PrepArgs pa) {
  int i = blockIdx.x * 256 + threadIdx.x;
  if (i >= pa.cum[8]) return;
  int s = 0;
  while (i >= pa.cum[s + 1]) s++;
  int li = i - pa.cum[s];
  int FOUT = pa.fout[s];
  int NT = FOUT >> 4;
  int sz = pa.cum[s + 1] - pa.cum[s];
  int c = li / (NT * 512);
  int r1 = li % (NT * 512);
  int t = r1 >> 9;
  int e = r1 & 511;
  int lane = e >> 3, j = e & 7;
  int k = c * 32 + (lane >> 4) * 8 + j;
  int n = t * 16 + (lane & 15);
  float v = pa.w[s][k * FOUT + n];
  short h, m, l;
  cvt3(v, h, m, l);
  pa.o[s][li] = h;
  pa.o[s][li + sz] = m;
  pa.o[s][li + 2 * sz] = l;
}

// 6-term triple-split MFMA accumulate for one tile
#define MFMA6(ah, am, al, bh, bm, bl, acc)                                   \
  acc = __builtin_amdgcn_mfma_f32_16x16x32_bf16(ah, bh, acc, 0, 0, 0);      \
  acc = __builtin_amdgcn_mfma_f32_16x16x32_bf16(ah, bm, acc, 0, 0, 0);      \
  acc = __builtin_amdgcn_mfma_f32_16x16x32_bf16(am, bh, acc, 0, 0, 0);      \
  acc = __builtin_amdgcn_mfma_f32_16x16x32_bf16(ah, bl, acc, 0, 0, 0);      \
  acc = __builtin_amdgcn_mfma_f32_16x16x32_bf16(am, bm, acc, 0, 0, 0);      \
  acc = __builtin_amdgcn_mfma_f32_16x16x32_bf16(al, bh, acc, 0, 0, 0);

// ---------- layer-0 GEMM: fused LN64 + X@WL and X@WR in one block ----------
// Row rA spread over 4 quads (16 elems each); xor-16/32 give row mean/var;
// normalize once, convert once, feed both W's MFMAs.
__global__ __launch_bounds__(256, 3) void mfma_gemm_ln_lr_kernel(
    const float* __restrict__ X, const float* __restrict__ lng,
    const float* __restrict__ lnb, const short* __restrict__ WfL,
    const short* __restrict__ WfR, float* __restrict__ YL,
    float* __restrict__ YR, int nrows) {
  constexpr int NT = 8, TOT = 2 * NT * 512;
  const int wave = threadIdx.x >> 6, lane = threadIdx.x & 63;
  const int quad = lane >> 4, ln16 = lane & 15;
  int rowA = blockIdx.x * 64 + wave * 16 + ln16;
  int rA = rowA < nrows ? rowA : nrows - 1;
  const float* xp = X + (size_t)rA * 64 + quad * 8;

  float av[16];
  *(float4*)&av[0]  = *(const float4*)(xp);
  *(float4*)&av[4]  = *(const float4*)(xp + 4);
  *(float4*)&av[8]  = *(const float4*)(xp + 32);
  *(float4*)&av[12] = *(const float4*)(xp + 36);

  float s = 0.f, sq = 0.f;
  #pragma unroll
  for (int j = 0; j < 16; j++) { s += av[j]; sq += av[j] * av[j]; }
  s  += __shfl_xor(s, 16);  s  += __shfl_xor(s, 32);
  sq += __shfl_xor(sq, 16); sq += __shfl_xor(sq, 32);
  float mean = s * (1.f / 64.f);
  float var = sq * (1.f / 64.f) - mean * mean;
  float rstd = rsqrtf(var + 1e-5f);

  f32x4 accL[NT], accR[NT];
  #pragma unroll
  for (int t = 0; t < NT; t++) {
    accL[t] = (f32x4){0.f, 0.f, 0.f, 0.f};
    accR[t] = (f32x4){0.f, 0.f, 0.f, 0.f};
  }

  #pragma unroll
  for (int c = 0; c < 2; c++) {
    float4 gv0 = *(const float4*)&lng[quad * 8 + c * 32];
    float4 gv1 = *(const float4*)&lng[quad * 8 + c * 32 + 4];
    float4 bv0 = *(const float4*)&lnb[quad * 8 + c * 32];
    float4 bv1 = *(const float4*)&lnb[quad * 8 + c * 32 + 4];
    float gg[8] = {gv0.x, gv0.y, gv0.z, gv0.w, gv1.x, gv1.y, gv1.z, gv1.w};
    float bb[8] = {bv0.x, bv0.y, bv0.z, bv0.w, bv1.x, bv1.y, bv1.z, bv1.w};
    short8 ah, am, al;
    #pragma unroll
    for (int j = 0; j < 8; j++) {
      float v = (av[c * 8 + j] - mean) * rstd * gg[j] + bb[j];
      short h, m, l;
      cvt3(v, h, m, l);
      ah[j] = h; am[j] = m; al[j] = l;
    }
    const short* wpL = WfL + c * NT * 512 + lane * 8;
    const short* wpR = WfR + c * NT * 512 + lane * 8;
    #pragma unroll
    for (int t = 0; t < NT; t++) {
      short8 bh = *(const short8*)(wpL + t * 512);
      short8 bm = *(const short8*)(wpL + t * 512 + TOT);
      short8 bl = *(const short8*)(wpL + t * 512 + 2 * TOT);
      MFMA6(ah, am, al, bh, bm, bl, accL[t]);
      short8 ch = *(const short8*)(wpR + t * 512);
      short8 cm = *(const short8*)(wpR + t * 512 + TOT);
      short8 cl = *(const short8*)(wpR + t * 512 + 2 * TOT);
      MFMA6(ah, am, al, ch, cm, cl, accR[t]);
    }
  }

  const int rbase = blockIdx.x * 64 + wave * 16 + quad * 4;
  #pragma unroll
  for (int t = 0; t < NT; t++)
    #pragma unroll
    for (int r = 0; r < 4; r++) {
      int rr = rbase + r;
      if (rr < nrows) {
        YL[(size_t)rr * 128 + t * 16 + ln16] = accL[t][r];
        YR[(size_t)rr * 128 + t * 16 + ln16] = accR[t][r];
      }
    }
}

// ---------- generic MFMA GEMM: FIN=128, YL=X@WL and YR=X@WR in one block ---
__global__ __launch_bounds__(256, 3) void mfma_gemm_lr_kernel(
    const float* __restrict__ X, const short* __restrict__ WfL,
    const short* __restrict__ WfR, float* __restrict__ YL,
    float* __restrict__ YR, int nrows) {
  constexpr int NC = 4, NT = 8, TOT = NC * NT * 512;
  const int wave = threadIdx.x >> 6, lane = threadIdx.x & 63;
  const int quad = lane >> 4, ln16 = lane & 15;
  int rowA = blockIdx.x * 64 + wave * 16 + ln16;
  int rA = rowA < nrows ? rowA : nrows - 1;
  const float* xp = X + (size_t)rA * 128 + quad * 8;

  f32x4 accL[NT], accR[NT];
  #pragma unroll
  for (int t = 0; t < NT; t++) {
    accL[t] = (f32x4){0.f, 0.f, 0.f, 0.f};
    accR[t] = (f32x4){0.f, 0.f, 0.f, 0.f};
  }

  #pragma unroll
  for (int c = 0; c < NC; c++) {
    float4 a0 = *(const float4*)(xp + c * 32);
    float4 a1 = *(const float4*)(xp + c * 32 + 4);
    float av[8] = {a0.x, a0.y, a0.z, a0.w, a1.x, a1.y, a1.z, a1.w};
    short8 ah, am, al;
    #pragma unroll
    for (int j = 0; j < 8; j++) {
      short h, m, l;
      cvt3(av[j], h, m, l);
      ah[j] = h; am[j] = m; al[j] = l;
    }
    const short* wpL = WfL + c * NT * 512 + lane * 8;
    const short* wpR = WfR + c * NT * 512 + lane * 8;
    #pragma unroll
    for (int t = 0; t < NT; t++) {
      short8 bh = *(const short8*)(wpL + t * 512);
      short8 bm = *(const short8*)(wpL + t * 512 + TOT);
      short8 bl = *(const short8*)(wpL + t * 512 + 2 * TOT);
      MFMA6(ah, am, al, bh, bm, bl, accL[t]);
      short8 ch = *(const short8*)(wpR + t * 512);
      short8 cm = *(const short8*)(wpR + t * 512 + TOT);
      short8 cl = *(const short8*)(wpR + t * 512 + 2 * TOT);
      MFMA6(ah, am, al, ch, cm, cl, accR[t]);
    }
  }

  const int rbase = blockIdx.x * 64 + wave * 16 + quad * 4;
  #pragma unroll
  for (int t = 0; t < NT; t++)
    #pragma unroll
    for (int r = 0; r < 4; r++) {
      int rr = rbase + r;
      if (rr < nrows) {
        YL[(size_t)rr * 128 + t * 16 + ln16] = accL[t][r];
        YR[(size_t)rr * 128 + t * 16 + ln16] = accR[t][r];
      }
    }
}

// ---------- head GEMMs fused with final dots: out[row,0..1] in one block ---
__global__ __launch_bounds__(256, 4) void mfma_head_lr_kernel(
    const float* __restrict__ X, const short* __restrict__ Wf1,
    const float* __restrict__ b1a, const float* __restrict__ w2a,
    const float* __restrict__ b2a, const short* __restrict__ Wf2,
    const float* __restrict__ b1b, const float* __restrict__ w2b,
    const float* __restrict__ b2b, float* __restrict__ out, int nrows) {
  constexpr int NC = 4, NT = 4, TOT = NC * NT * 512;
  const int wave = threadIdx.x >> 6, lane = threadIdx.x & 63;
  const int quad = lane >> 4, ln16 = lane & 15;
  int rowA = blockIdx.x * 64 + wave * 16 + ln16;
  int rA = rowA < nrows ? rowA : nrows - 1;
  const float* xp = X + (size_t)rA * 128 + quad * 8;

  f32x4 accL[NT], accR[NT];
  #pragma unroll
  for (int t = 0; t < NT; t++) {
    accL[t] = (f32x4){0.f, 0.f, 0.f, 0.f};
    accR[t] = (f32x4){0.f, 0.f, 0.f, 0.f};
  }

  #pragma unroll
  for (int c = 0; c < NC; c++) {
    float4 a0 = *(const float4*)(xp + c * 32);
    float4 a1 = *(const float4*)(xp + c * 32 + 4);
    float av[8] = {a0.x, a0.y, a0.z, a0.w, a1.x, a1.y, a1.z, a1.w};
    short8 ah, am, al;
    #pragma unroll
    for (int j = 0; j < 8; j++) {
      short h, m, l;
      cvt3(av[j], h, m, l);
      ah[j] = h; am[j] = m; al[j] = l;
    }
    const short* wpL = Wf1 + c * NT * 512 + lane * 8;
    const short* wpR = Wf2 + c * NT * 512 + lane * 8;
    #pragma unroll
    for (int t = 0; t < NT; t++) {
      short8 bh = *(const short8*)(wpL + t * 512);
      short8 bm = *(const short8*)(wpL + t * 512 + TOT);
      short8 bl = *(const short8*)(wpL + t * 512 + 2 * TOT);
      MFMA6(ah, am, al, bh, bm, bl, accL[t]);
      short8 ch = *(const short8*)(wpR + t * 512);
      short8 cm = *(const short8*)(wpR + t * 512 + TOT);
      short8 cl = *(const short8*)(wpR + t * 512 + 2 * TOT);
      MFMA6(ah, am, al, ch, cm, cl, accR[t]);
    }
  }

  float prA[4] = {0.f, 0.f, 0.f, 0.f};
  float prB[4] = {0.f, 0.f, 0.f, 0.f};
  #pragma unroll
  for (int t = 0; t < NT; t++) {
    float bvA = b1a[t * 16 + ln16], wvA = w2a[t * 16 + ln16];
    float bvB = b1b[t * 16 + ln16], wvB = w2b[t * 16 + ln16];
    #pragma unroll
    for (int r = 0; r < 4; r++) {
      prA[r] += fmaxf(accL[t][r] + bvA, 0.f) * wvA;
      prB[r] += fmaxf(accR[t][r] + bvB, 0.f) * wvB;
    }
  }
  #pragma unroll
  for (int o = 1; o < 16; o <<= 1)
    #pragma unroll
    for (int r = 0; r < 4; r++) {
      prA[r] += __shfl_xor(prA[r], o);
      prB[r] += __shfl_xor(prB[r], o);
    }
  if (ln16 == 0) {
    const float bb2a = b2a[0], bb2b = b2b[0];
    const int rbase = blockIdx.x * 64 + wave * 16 + quad * 4;
    #pragma unroll
    for (int r = 0; r < 4; r++) {
      int rr = rbase + r;
      if (rr < nrows) {
        out[(size_t)rr * 2 + 0] = prA[r] + bb2a;
        out[(size_t)rr * 2 + 1] = prB[r] + bb2b;
      }
    }
  }
}

// ---------- fused GAT layer -------------------------------------------------
// Wave per dst row; each 16-lane QUARTER processes its own edge stream
// (lane owns 8 channels = 2xfloat4) -> 8 loads in flight/wave. Plain softmax
// sums; quarters combine via xor-16/32 adds. Fused LN + residual + relu.
// leaky_relu(v) = max(v, 0.2v) exactly (slope < 1).
template <int H>
__global__ __launch_bounds__(256) void gat_fused_kernel(
    const float* __restrict__ xl, const float* __restrict__ xr,
    const int* __restrict__ csr_src, const int* __restrict__ row_end,
    const int* __restrict__ deg, const float* __restrict__ att,
    const float* __restrict__ res, const float* __restrict__ g,
    const float* __restrict__ b, float* __restrict__ y, int n,
    float resScale, int doRelu) {
  int row = blockIdx.x * 4 + (threadIdx.x >> 6);
  if (row >= n) return;
  int l = threadIdx.x & 63;
  int q = l >> 4;
  int ln = l & 15;
  int cb = ln * 32;  // byte offset of lane's 8-channel chunk
  int end = row_end[row];
  int dg = deg[row];
  int start = end - dg;
  int cnt = (dg - q + 3) >> 2;  // edges for this quarter (dg >= 1 always)

  const char* xrb = (const char*)xr + (size_t)row * 512 + cb;
  f4v xr0 = __builtin_nontemporal_load((const f4v*)xrb);
  f4v xr1 = __builtin_nontemporal_load((const f4v*)(xrb + 16));
  f4v av0 = *(const f4v*)((const char*)att + cb);
  f4v av1 = *(const f4v*)((const char*)att + cb + 16);

  float s = 0.f;
  float ac[8] = {0.f, 0.f, 0.f, 0.f, 0.f, 0.f, 0.f, 0.f};

  int idx = start + q;
  f4v xn0 = {0.f, 0.f, 0.f, 0.f}, xn1 = {0.f, 0.f, 0.f, 0.f};
  if (cnt > 0) {
    const char* p = (const char*)xl + (size_t)csr_src[idx] * 512 + cb;
    xn0 = *(const f4v*)p;
    xn1 = *(const f4v*)(p + 16);
  }
  for (int i = 0; i < cnt; i++) {
    f4v x0 = xn0, x1 = xn1;
    if (i + 1 < cnt) {
      const char* p = (const char*)xl + (size_t)csr_src[idx + 4] * 512 + cb;
      xn0 = *(const f4v*)p;
      xn1 = *(const f4v*)(p + 16);
    }
    idx += 4;
    float p0;
    {
      float t0 = x0.x + xr0.x, t1 = x0.y + xr0.y;
      float t2 = x0.z + xr0.z, t3 = x0.w + xr0.w;
      float t4 = x1.x + xr1.x, t5 = x1.y + xr1.y;
      float t6 = x1.z + xr1.z, t7 = x1.w + xr1.w;
      float v0 = fmaxf(t0, NEG_SLOPE * t0), v1 = fmaxf(t1, NEG_SLOPE * t1);
      float v2 = fmaxf(t2, NEG_SLOPE * t2), v3 = fmaxf(t3, NEG_SLOPE * t3);
      float v4 = fmaxf(t4, NEG_SLOPE * t4), v5 = fmaxf(t5, NEG_SLOPE * t5);
      float v6 = fmaxf(t6, NEG_SLOPE * t6), v7 = fmaxf(t7, NEG_SLOPE * t7);
      p0 = v0 * av0.x + v1 * av0.y + v2 * av0.z + v3 * av0.w +
           v4 * av1.x + v5 * av1.y + v6 * av1.z + v7 * av1.w;
    }
    if constexpr (H == 1) {  // logit over 128 ch = 16 lanes
      #pragma unroll
      for (int o = 1; o < 16; o <<= 1) p0 += __shfl_xor(p0, o);
    } else {                 // H=4: head = 32 ch = 4 lanes
      p0 += __shfl_xor(p0, 1);
      p0 += __shfl_xor(p0, 2);
    }
    float e = __expf(p0);
    s += e;
    ac[0] += e * x0.x; ac[1] += e * x0.y; ac[2] += e * x0.z; ac[3] += e * x0.w;
    ac[4] += e * x1.x; ac[5] += e * x1.y; ac[6] += e * x1.z; ac[7] += e * x1.w;
  }
  // combine the four quarter streams (plain sums)
  s += __shfl_xor(s, 16);
  s += __shfl_xor(s, 32);
  #pragma unroll
  for (int j = 0; j < 8; j++) {
    ac[j] += __shfl_xor(ac[j], 16);
    ac[j] += __shfl_xor(ac[j], 32);
  }

  float inv = 1.f / s;
  float ov[8];
  #pragma unroll
  for (int j = 0; j < 8; j++) ov[j] = ac[j] * inv;

  // LayerNorm over 128 (16 lanes of a quarter cover all channels)
  float sum = 0.f, sq = 0.f;
  #pragma unroll
  for (int j = 0; j < 8; j++) { sum += ov[j]; sq += ov[j] * ov[j]; }
  #pragma unroll
  for (int o = 1; o < 16; o <<= 1) {
    sum += __shfl_xor(sum, o);
    sq += __shfl_xor(sq, o);
  }
  float mean = sum * (1.f / 128.f);
  float var = sq * (1.f / 128.f) - mean * mean;
  float rstd = rsqrtf(var + 1e-5f);

  f4v gv0 = *(const f4v*)((const char*)g + cb);
  f4v gv1 = *(const f4v*)((const char*)g + cb + 16);
  f4v bv0 = *(const f4v*)((const char*)b + cb);
  f4v bv1 = *(const f4v*)((const char*)b + cb + 16);
  float gg[8] = {gv0.x, gv0.y, gv0.z, gv0.w, gv1.x, gv1.y, gv1.z, gv1.w};
  float bb[8] = {bv0.x, bv0.y, bv0.z, bv0.w, bv1.x, bv1.y, bv1.z, bv1.w};
  float rv[8];
  #pragma unroll
  for (int j = 0; j < 8; j++) rv[j] = (ov[j] - mean) * rstd * gg[j] + bb[j];
  if (res) {
    const char* rb = (const char*)res + (size_t)row * 512 + cb;
    f4v r0 = __builtin_nontemporal_load((const f4v*)rb);
    f4v r1 = __builtin_nontemporal_load((const f4v*)(rb + 16));
    rv[0] += resScale * r0.x; rv[1] += resScale * r0.y;
    rv[2] += resScale * r0.z; rv[3] += resScale * r0.w;
    rv[4] += resScale * r1.x; rv[5] += resScale * r1.y;
    rv[6] += resScale * r1.z; rv[7] += resScale * r1.w;
  }
  if (doRelu) {
    #pragma unroll
    for (int j = 0; j < 8; j++) rv[j] = fmaxf(rv[j], 0.f);
  }
  if (q == 0) {
    char* yb = (char*)y + (size_t)row * 512 + cb;
    *(f4v*)yb = (f4v){rv[0], rv[1], rv[2], rv[3]};
    *(f4v*)(yb + 16) = (f4v){rv[4], rv[5], rv[6], rv[7]};
  }
}

// ---------- launch ----------
extern "C" void kernel_launch(void* const* d_in, const int* in_sizes, int n_in,
                              void* d_out, int out_size, void* d_ws,
                              size_t ws_size, hipStream_t stream) {
  const float* x       = (const float*)d_in[0];
  const int*   ei      = (const int*)d_in[1];
  const float* ln_in_g = (const float*)d_in[2];
  const float* ln_in_b = (const float*)d_in[3];
  const float* w_l1    = (const float*)d_in[4];
  const float* w_r1    = (const float*)d_in[5];
  const float* att1    = (const float*)d_in[6];
  const float* ln1_g   = (const float*)d_in[7];
  const float* ln1_b   = (const float*)d_in[8];
  const float* w_l2    = (const float*)d_in[9];
  const float* w_r2    = (const float*)d_in[10];
  const float* att2    = (const float*)d_in[11];
  const float* ln2_g   = (const float*)d_in[12];
  const float* ln2_b   = (const float*)d_in[13];
  const float* w_l3    = (const float*)d_in[14];
  const float* w_r3    = (const float*)d_in[15];
  const float* att3    = (const float*)d_in[16];
  const float* ln3_g   = (const float*)d_in[17];
  const float* ln3_b   = (const float*)d_in[18];
  const float* rtt_w1  = (const float*)d_in[19];
  const float* rtt_b1  = (const float*)d_in[20];
  const float* rtt_w2  = (const float*)d_in[21];
  const float* rtt_b2  = (const float*)d_in[22];
  const float* ret_w1  = (const float*)d_in[23];
  const float* ret_b1  = (const float*)d_in[24];
  const float* ret_w2  = (const float*)d_in[25];
  const float* ret_b2  = (const float*)d_in[26];

  const int N = in_sizes[0] / 64;
  const int E = in_sizes[1] / 2;
  const int ET = E + N;
  const size_t NF = (size_t)N * 128;

  float* A = (float*)d_ws;            // node features h / residual
  float* B = A + NF;                  // xl
  float* C = B + NF;                  // xr
  int* deg     = (int*)(C + NF);      // N
  int* rowcur  = deg + N;             // N (row_end after scatter)
  int* incl    = rowcur + N;          // N
  int* bsums   = incl + N;            // 1024
  int* csr_src = bsums + 1024;        // ET
  short* wf = (short*)(((uintptr_t)(csr_src + ET) + 63) & ~(uintptr_t)63);

  float* out = (float*)d_out;

  // segments: wl1, wr1, wl2, wr2, wl3, wr3, rtt_w1, ret_w1
  const int segsz[8] = {64 * 128, 64 * 128, 128 * 128, 128 * 128,
                        128 * 128, 128 * 128, 128 * 64, 128 * 64};
  PrepArgs pa;
  pa.w[0] = w_l1; pa.w[1] = w_r1; pa.w[2] = w_l2; pa.w[3] = w_r2;
  pa.w[4] = w_l3; pa.w[5] = w_r3; pa.w[6] = rtt_w1; pa.w[7] = ret_w1;
  pa.fout[0] = 128; pa.fout[1] = 128; pa.fout[2] = 128; pa.fout[3] = 128;
  pa.fout[4] = 128; pa.fout[5] = 128; pa.fout[6] = 64; pa.fout[7] = 64;
  int acc = 0;
  short* op = wf;
  for (int s = 0; s < 8; s++) {
    pa.cum[s] = acc;
    pa.o[s] = op;
    op += 3 * segsz[s];  // h + m + l planes
    acc += segsz[s];
  }
  pa.cum[8] = acc;

  const int rowBlocks  = (N + 3) / 4;
  const int mmBlocks   = (N + 63) / 64;
  const int NB = (N + 1023) / 1024;

  // ---- W fragment prep ----
  prep_w_kernel<<<(acc + 255) / 256, 256, 0, stream>>>(pa);

  // ---- CSR build (by dst) ----
  fill_ones_kernel<<<(N + 255) / 256, 256, 0, stream>>>(deg, N);
  degree_count_kernel<<<(E + 255) / 256, 256, 0, stream>>>(ei, E, deg);
  scan1_kernel<<<NB, 1024, 0, stream>>>(deg, N, incl, bsums);
  scan2_kernel<<<1, 1024, 0, stream>>>(bsums, NB);
  scan3_kernel<<<NB, 1024, 0, stream>>>(incl, deg, bsums, N, rowcur);
  scatter_kernel<<<(ET + 255) / 256, 256, 0, stream>>>(ei, E, ET, rowcur, csr_src);

  // ---- layer 0: fused LN64 + GEMM 64->128 (L+R), 4 heads, relu ----
  mfma_gemm_ln_lr_kernel<<<mmBlocks, 256, 0, stream>>>(
      x, ln_in_g, ln_in_b, pa.o[0], pa.o[1], B, C, N);
  gat_fused_kernel<4><<<rowBlocks, 256, 0, stream>>>(
      B, C, csr_src, rowcur, deg, att1, nullptr, ln1_g, ln1_b, A, N, 0.f, 1);

  // ---- layer 1: 128 -> 128 (L+R), 4 heads, residual 0.1, relu ----
  mfma_gemm_lr_kernel<<<mmBlocks, 256, 0, stream>>>(A, pa.o[2], pa.o[3], B, C, N);
  gat_fused_kernel<4><<<rowBlocks, 256, 0, stream>>>(
      B, C, csr_src, rowcur, deg, att2, A, ln2_g, ln2_b, A, N, 0.1f, 1);

  // ---- layer 2: 128 -> 128 (L+R), 1 head, residual 0.1, no relu ----
  mfma_gemm_lr_kernel<<<mmBlocks, 256, 0, stream>>>(A, pa.o[4], pa.o[5], B, C, N);
  gat_fused_kernel<1><<<rowBlocks, 256, 0, stream>>>(
      B, C, csr_src, rowcur, deg, att3, A, ln3_g, ln3_b, A, N, 0.1f, 0);

  // ---- prediction heads: both GEMMs + relu + final dots in one dispatch ----
  mfma_head_lr_kernel<<<mmBlocks, 256, 0, stream>>>(
      A, pa.o[6], rtt_b1, rtt_w2, rtt_b2, pa.o[7], ret_b1, ret_w2, ret_b2,
      out, N);
}

// Round 10
// 718.983 us; speedup vs baseline: 1.0377x; 1.0377x over previous
//
#include <hip/hip_runtime.h>
#include <hip/hip_bf16.h>
#include <cstdint>
#include <cstddef>

#define NEG_SLOPE 0.2f

typedef float f4v __attribute__((ext_vector_type(4)));
typedef short short8 __attribute__((ext_vector_type(8)));
typedef float f32x4 __attribute__((ext_vector_type(4)));

// fp32 -> 3x bf16 (h,m exact chops; l = RN of remainder). h+m+l = v to
// ~2^-24 rel. GEMM keeps products {hh,hm,mh,hl,mm,lh} -> fp32-grade result.
__device__ __forceinline__ void cvt3(float v, short& h, short& m, short& l) {
  unsigned u = __builtin_bit_cast(unsigned, v);
  h = (short)(u >> 16);
  float hf = __builtin_bit_cast(float, u & 0xFFFF0000u);
  float r1 = v - hf;
  unsigned u1 = __builtin_bit_cast(unsigned, r1);
  m = (short)(u1 >> 16);
  float mf = __builtin_bit_cast(float, u1 & 0xFFFF0000u);
  l = __builtin_bit_cast(short, __float2bfloat16(r1 - mf));
}

// ---------- CSR build ----------

__global__ __launch_bounds__(256) void fill_ones_kernel(int* __restrict__ p, int n) {
  int i = blockIdx.x * 256 + threadIdx.x;
  if (i < n) p[i] = 1;  // self-loop contributes degree 1
}

__global__ __launch_bounds__(256) void degree_count_kernel(
    const int* __restrict__ ei, int E, int* __restrict__ deg) {
  int e = blockIdx.x * 256 + threadIdx.x;
  if (e < E) atomicAdd(&deg[ei[E + e]], 1);
}

__global__ __launch_bounds__(1024) void scan1_kernel(
    const int* __restrict__ deg, int n, int* __restrict__ incl,
    int* __restrict__ blocksums) {
  __shared__ int sm[1024];
  int t = threadIdx.x;
  int i = blockIdx.x * 1024 + t;
  sm[t] = (i < n) ? deg[i] : 0;
  __syncthreads();
  #pragma unroll
  for (int o = 1; o < 1024; o <<= 1) {
    int a = (t >= o) ? sm[t - o] : 0;
    __syncthreads();
    sm[t] += a;
    __syncthreads();
  }
  if (i < n) incl[i] = sm[t];
  if (t == 1023) blocksums[blockIdx.x] = sm[t];
}

__global__ __launch_bounds__(1024) void scan2_kernel(int* __restrict__ bs, int nb) {
  __shared__ int sm[1024];
  int t = threadIdx.x;
  sm[t] = (t < nb) ? bs[t] : 0;
  __syncthreads();
  #pragma unroll
  for (int o = 1; o < 1024; o <<= 1) {
    int a = (t >= o) ? sm[t - o] : 0;
    __syncthreads();
    sm[t] += a;
    __syncthreads();
  }
  if (t < nb) bs[t] = sm[t];
}

__global__ __launch_bounds__(1024) void scan3_kernel(
    const int* __restrict__ incl, const int* __restrict__ deg,
    const int* __restrict__ bs, int n, int* __restrict__ rowcur) {
  int i = blockIdx.x * 1024 + threadIdx.x;
  if (i >= n) return;
  int off = (blockIdx.x > 0) ? bs[blockIdx.x - 1] : 0;
  rowcur[i] = incl[i] - deg[i] + off;
}

__global__ __launch_bounds__(256) void scatter_kernel(
    const int* __restrict__ ei, int E, int ET, int* __restrict__ rowcur,
    int* __restrict__ csr_src) {
  int e = blockIdx.x * 256 + threadIdx.x;
  if (e >= ET) return;
  int s, d;
  if (e < E) { s = ei[e]; d = ei[E + e]; }
  else       { s = e - E; d = s; }
  int pos = atomicAdd(&rowcur[d], 1);
  csr_src[pos] = s;
}

// ---------- W -> MFMA B-fragment layout (triple bf16 planes) ----------
struct PrepArgs {
  const float* w[8];
  short* o[8];
  int fout[8];
  int cum[9];
};

__global__ __launch_bounds__(256) void prep_w_kernel(PrepArgs pa) {
  int i = blockIdx.x * 256 + threadIdx.x;
  if (i >= pa.cum[8]) return;
  int s = 0;
  while (i >= pa.cum[s + 1]) s++;
  int li = i - pa.cum[s];
  int FOUT = pa.fout[s];
  int NT = FOUT >> 4;
  int sz = pa.cum[s + 1] - pa.cum[s];
  int c = li / (NT * 512);
  int r1 = li % (NT * 512);
  int t = r1 >> 9;
  int e = r1 & 511;
  int lane = e >> 3, j = e & 7;
  int k = c * 32 + (lane >> 4) * 8 + j;
  int n = t * 16 + (lane & 15);
  float v = pa.w[s][k * FOUT + n];
  short h, m, l;
  cvt3(v, h, m, l);
  pa.o[s][li] = h;
  pa.o[s][li + sz] = m;
  pa.o[s][li + 2 * sz] = l;
}

// 6-term triple-split MFMA accumulate for one tile
#define MFMA6(ah, am, al, bh, bm, bl, acc)                                   \
  acc = __builtin_amdgcn_mfma_f32_16x16x32_bf16(ah, bh, acc, 0, 0, 0);      \
  acc = __builtin_amdgcn_mfma_f32_16x16x32_bf16(ah, bm, acc, 0, 0, 0);      \
  acc = __builtin_amdgcn_mfma_f32_16x16x32_bf16(am, bh, acc, 0, 0, 0);      \
  acc = __builtin_amdgcn_mfma_f32_16x16x32_bf16(ah, bl, acc, 0, 0, 0);      \
  acc = __builtin_amdgcn_mfma_f32_16x16x32_bf16(am, bm, acc, 0, 0, 0);      \
  acc = __builtin_amdgcn_mfma_f32_16x16x32_bf16(al, bh, acc, 0, 0, 0);

// ---------- layer-0 GEMM: fused LN64 + X@WL and X@WR in one block ----------
// __launch_bounds__(256,1): full 512-VGPR budget -> no scratch spill (r9's
// (256,3) made the allocator pick 84 VGPRs + 240 MB spill traffic).
__global__ __launch_bounds__(256, 1) void mfma_gemm_ln_lr_kernel(
    const float* __restrict__ X, const float* __restrict__ lng,
    const float* __restrict__ lnb, const short* __restrict__ WfL,
    const short* __restrict__ WfR, float* __restrict__ YL,
    float* __restrict__ YR, int nrows) {
  constexpr int NT = 8, TOT = 2 * NT * 512;
  const int wave = threadIdx.x >> 6, lane = threadIdx.x & 63;
  const int quad = lane >> 4, ln16 = lane & 15;
  int rowA = blockIdx.x * 64 + wave * 16 + ln16;
  int rA = rowA < nrows ? rowA : nrows - 1;
  const float* xp = X + (size_t)rA * 64 + quad * 8;

  float av[16];
  *(float4*)&av[0]  = *(const float4*)(xp);
  *(float4*)&av[4]  = *(const float4*)(xp + 4);
  *(float4*)&av[8]  = *(const float4*)(xp + 32);
  *(float4*)&av[12] = *(const float4*)(xp + 36);

  float s = 0.f, sq = 0.f;
  #pragma unroll
  for (int j = 0; j < 16; j++) { s += av[j]; sq += av[j] * av[j]; }
  s  += __shfl_xor(s, 16);  s  += __shfl_xor(s, 32);
  sq += __shfl_xor(sq, 16); sq += __shfl_xor(sq, 32);
  float mean = s * (1.f / 64.f);
  float var = sq * (1.f / 64.f) - mean * mean;
  float rstd = rsqrtf(var + 1e-5f);

  f32x4 accL[NT], accR[NT];
  #pragma unroll
  for (int t = 0; t < NT; t++) {
    accL[t] = (f32x4){0.f, 0.f, 0.f, 0.f};
    accR[t] = (f32x4){0.f, 0.f, 0.f, 0.f};
  }

  #pragma unroll
  for (int c = 0; c < 2; c++) {
    float4 gv0 = *(const float4*)&lng[quad * 8 + c * 32];
    float4 gv1 = *(const float4*)&lng[quad * 8 + c * 32 + 4];
    float4 bv0 = *(const float4*)&lnb[quad * 8 + c * 32];
    float4 bv1 = *(const float4*)&lnb[quad * 8 + c * 32 + 4];
    float gg[8] = {gv0.x, gv0.y, gv0.z, gv0.w, gv1.x, gv1.y, gv1.z, gv1.w};
    float bb[8] = {bv0.x, bv0.y, bv0.z, bv0.w, bv1.x, bv1.y, bv1.z, bv1.w};
    short8 ah, am, al;
    #pragma unroll
    for (int j = 0; j < 8; j++) {
      float v = (av[c * 8 + j] - mean) * rstd * gg[j] + bb[j];
      short h, m, l;
      cvt3(v, h, m, l);
      ah[j] = h; am[j] = m; al[j] = l;
    }
    const short* wpL = WfL + c * NT * 512 + lane * 8;
    const short* wpR = WfR + c * NT * 512 + lane * 8;
    #pragma unroll
    for (int t = 0; t < NT; t++) {
      short8 bh = *(const short8*)(wpL + t * 512);
      short8 bm = *(const short8*)(wpL + t * 512 + TOT);
      short8 bl = *(const short8*)(wpL + t * 512 + 2 * TOT);
      MFMA6(ah, am, al, bh, bm, bl, accL[t]);
      short8 ch = *(const short8*)(wpR + t * 512);
      short8 cm = *(const short8*)(wpR + t * 512 + TOT);
      short8 cl = *(const short8*)(wpR + t * 512 + 2 * TOT);
      MFMA6(ah, am, al, ch, cm, cl, accR[t]);
    }
  }

  const int rbase = blockIdx.x * 64 + wave * 16 + quad * 4;
  #pragma unroll
  for (int t = 0; t < NT; t++)
    #pragma unroll
    for (int r = 0; r < 4; r++) {
      int rr = rbase + r;
      if (rr < nrows) {
        YL[(size_t)rr * 128 + t * 16 + ln16] = accL[t][r];
        YR[(size_t)rr * 128 + t * 16 + ln16] = accR[t][r];
      }
    }
}

// ---------- generic MFMA GEMM: FIN=128, YL=X@WL and YR=X@WR in one block ---
__global__ __launch_bounds__(256, 1) void mfma_gemm_lr_kernel(
    const float* __restrict__ X, const short* __restrict__ WfL,
    const short* __restrict__ WfR, float* __restrict__ YL,
    float* __restrict__ YR, int nrows) {
  constexpr int NC = 4, NT = 8, TOT = NC * NT * 512;
  const int wave = threadIdx.x >> 6, lane = threadIdx.x & 63;
  const int quad = lane >> 4, ln16 = lane & 15;
  int rowA = blockIdx.x * 64 + wave * 16 + ln16;
  int rA = rowA < nrows ? rowA : nrows - 1;
  const float* xp = X + (size_t)rA * 128 + quad * 8;

  f32x4 accL[NT], accR[NT];
  #pragma unroll
  for (int t = 0; t < NT; t++) {
    accL[t] = (f32x4){0.f, 0.f, 0.f, 0.f};
    accR[t] = (f32x4){0.f, 0.f, 0.f, 0.f};
  }

  #pragma unroll
  for (int c = 0; c < NC; c++) {
    float4 a0 = *(const float4*)(xp + c * 32);
    float4 a1 = *(const float4*)(xp + c * 32 + 4);
    float av[8] = {a0.x, a0.y, a0.z, a0.w, a1.x, a1.y, a1.z, a1.w};
    short8 ah, am, al;
    #pragma unroll
    for (int j = 0; j < 8; j++) {
      short h, m, l;
      cvt3(av[j], h, m, l);
      ah[j] = h; am[j] = m; al[j] = l;
    }
    const short* wpL = WfL + c * NT * 512 + lane * 8;
    const short* wpR = WfR + c * NT * 512 + lane * 8;
    #pragma unroll
    for (int t = 0; t < NT; t++) {
      short8 bh = *(const short8*)(wpL + t * 512);
      short8 bm = *(const short8*)(wpL + t * 512 + TOT);
      short8 bl = *(const short8*)(wpL + t * 512 + 2 * TOT);
      MFMA6(ah, am, al, bh, bm, bl, accL[t]);
      short8 ch = *(const short8*)(wpR + t * 512);
      short8 cm = *(const short8*)(wpR + t * 512 + TOT);
      short8 cl = *(const short8*)(wpR + t * 512 + 2 * TOT);
      MFMA6(ah, am, al, ch, cm, cl, accR[t]);
    }
  }

  const int rbase = blockIdx.x * 64 + wave * 16 + quad * 4;
  #pragma unroll
  for (int t = 0; t < NT; t++)
    #pragma unroll
    for (int r = 0; r < 4; r++) {
      int rr = rbase + r;
      if (rr < nrows) {
        YL[(size_t)rr * 128 + t * 16 + ln16] = accL[t][r];
        YR[(size_t)rr * 128 + t * 16 + ln16] = accR[t][r];
      }
    }
}

// ---------- head GEMMs fused with final dots: out[row,0..1] in one block ---
__global__ __launch_bounds__(256, 2) void mfma_head_lr_kernel(
    const float* __restrict__ X, const short* __restrict__ Wf1,
    const float* __restrict__ b1a, const float* __restrict__ w2a,
    const float* __restrict__ b2a, const short* __restrict__ Wf2,
    const float* __restrict__ b1b, const float* __restrict__ w2b,
    const float* __restrict__ b2b, float* __restrict__ out, int nrows) {
  constexpr int NC = 4, NT = 4, TOT = NC * NT * 512;
  const int wave = threadIdx.x >> 6, lane = threadIdx.x & 63;
  const int quad = lane >> 4, ln16 = lane & 15;
  int rowA = blockIdx.x * 64 + wave * 16 + ln16;
  int rA = rowA < nrows ? rowA : nrows - 1;
  const float* xp = X + (size_t)rA * 128 + quad * 8;

  f32x4 accL[NT], accR[NT];
  #pragma unroll
  for (int t = 0; t < NT; t++) {
    accL[t] = (f32x4){0.f, 0.f, 0.f, 0.f};
    accR[t] = (f32x4){0.f, 0.f, 0.f, 0.f};
  }

  #pragma unroll
  for (int c = 0; c < NC; c++) {
    float4 a0 = *(const float4*)(xp + c * 32);
    float4 a1 = *(const float4*)(xp + c * 32 + 4);
    float av[8] = {a0.x, a0.y, a0.z, a0.w, a1.x, a1.y, a1.z, a1.w};
    short8 ah, am, al;
    #pragma unroll
    for (int j = 0; j < 8; j++) {
      short h, m, l;
      cvt3(av[j], h, m, l);
      ah[j] = h; am[j] = m; al[j] = l;
    }
    const short* wpL = Wf1 + c * NT * 512 + lane * 8;
    const short* wpR = Wf2 + c * NT * 512 + lane * 8;
    #pragma unroll
    for (int t = 0; t < NT; t++) {
      short8 bh = *(const short8*)(wpL + t * 512);
      short8 bm = *(const short8*)(wpL + t * 512 + TOT);
      short8 bl = *(const short8*)(wpL + t * 512 + 2 * TOT);
      MFMA6(ah, am, al, bh, bm, bl, accL[t]);
      short8 ch = *(const short8*)(wpR + t * 512);
      short8 cm = *(const short8*)(wpR + t * 512 + TOT);
      short8 cl = *(const short8*)(wpR + t * 512 + 2 * TOT);
      MFMA6(ah, am, al, ch, cm, cl, accR[t]);
    }
  }

  float prA[4] = {0.f, 0.f, 0.f, 0.f};
  float prB[4] = {0.f, 0.f, 0.f, 0.f};
  #pragma unroll
  for (int t = 0; t < NT; t++) {
    float bvA = b1a[t * 16 + ln16], wvA = w2a[t * 16 + ln16];
    float bvB = b1b[t * 16 + ln16], wvB = w2b[t * 16 + ln16];
    #pragma unroll
    for (int r = 0; r < 4; r++) {
      prA[r] += fmaxf(accL[t][r] + bvA, 0.f) * wvA;
      prB[r] += fmaxf(accR[t][r] + bvB, 0.f) * wvB;
    }
  }
  #pragma unroll
  for (int o = 1; o < 16; o <<= 1)
    #pragma unroll
    for (int r = 0; r < 4; r++) {
      prA[r] += __shfl_xor(prA[r], o);
      prB[r] += __shfl_xor(prB[r], o);
    }
  if (ln16 == 0) {
    const float bb2a = b2a[0], bb2b = b2b[0];
    const int rbase = blockIdx.x * 64 + wave * 16 + quad * 4;
    #pragma unroll
    for (int r = 0; r < 4; r++) {
      int rr = rbase + r;
      if (rr < nrows) {
        out[(size_t)rr * 2 + 0] = prA[r] + bb2a;
        out[(size_t)rr * 2 + 1] = prB[r] + bb2b;
      }
    }
  }
}

// ---------- fused GAT layer -------------------------------------------------
// Wave per dst row; each 16-lane QUARTER processes its own edge stream
// (lane owns 8 channels = 2xfloat4) -> 8 loads in flight/wave. Plain softmax
// sums; quarters combine via xor-16/32 adds. Fused LN + residual + relu.
// leaky_relu(v) = max(v, 0.2v) exactly (slope < 1).
template <int H>
__global__ __launch_bounds__(256) void gat_fused_kernel(
    const float* __restrict__ xl, const float* __restrict__ xr,
    const int* __restrict__ csr_src, const int* __restrict__ row_end,
    const int* __restrict__ deg, const float* __restrict__ att,
    const float* __restrict__ res, const float* __restrict__ g,
    const float* __restrict__ b, float* __restrict__ y, int n,
    float resScale, int doRelu) {
  int row = blockIdx.x * 4 + (threadIdx.x >> 6);
  if (row >= n) return;
  int l = threadIdx.x & 63;
  int q = l >> 4;
  int ln = l & 15;
  int cb = ln * 32;  // byte offset of lane's 8-channel chunk
  int end = row_end[row];
  int dg = deg[row];
  int start = end - dg;
  int cnt = (dg - q + 3) >> 2;  // edges for this quarter (dg >= 1 always)

  const char* xrb = (const char*)xr + (size_t)row * 512 + cb;
  f4v xr0 = __builtin_nontemporal_load((const f4v*)xrb);
  f4v xr1 = __builtin_nontemporal_load((const f4v*)(xrb + 16));
  f4v av0 = *(const f4v*)((const char*)att + cb);
  f4v av1 = *(const f4v*)((const char*)att + cb + 16);

  float s = 0.f;
  float ac[8] = {0.f, 0.f, 0.f, 0.f, 0.f, 0.f, 0.f, 0.f};

  int idx = start + q;
  f4v xn0 = {0.f, 0.f, 0.f, 0.f}, xn1 = {0.f, 0.f, 0.f, 0.f};
  if (cnt > 0) {
    const char* p = (const char*)xl + (size_t)csr_src[idx] * 512 + cb;
    xn0 = *(const f4v*)p;
    xn1 = *(const f4v*)(p + 16);
  }
  for (int i = 0; i < cnt; i++) {
    f4v x0 = xn0, x1 = xn1;
    if (i + 1 < cnt) {
      const char* p = (const char*)xl + (size_t)csr_src[idx + 4] * 512 + cb;
      xn0 = *(const f4v*)p;
      xn1 = *(const f4v*)(p + 16);
    }
    idx += 4;
    float p0;
    {
      float t0 = x0.x + xr0.x, t1 = x0.y + xr0.y;
      float t2 = x0.z + xr0.z, t3 = x0.w + xr0.w;
      float t4 = x1.x + xr1.x, t5 = x1.y + xr1.y;
      float t6 = x1.z + xr1.z, t7 = x1.w + xr1.w;
      float v0 = fmaxf(t0, NEG_SLOPE * t0), v1 = fmaxf(t1, NEG_SLOPE * t1);
      float v2 = fmaxf(t2, NEG_SLOPE * t2), v3 = fmaxf(t3, NEG_SLOPE * t3);
      float v4 = fmaxf(t4, NEG_SLOPE * t4), v5 = fmaxf(t5, NEG_SLOPE * t5);
      float v6 = fmaxf(t6, NEG_SLOPE * t6), v7 = fmaxf(t7, NEG_SLOPE * t7);
      p0 = v0 * av0.x + v1 * av0.y + v2 * av0.z + v3 * av0.w +
           v4 * av1.x + v5 * av1.y + v6 * av1.z + v7 * av1.w;
    }
    if constexpr (H == 1) {  // logit over 128 ch = 16 lanes
      #pragma unroll
      for (int o = 1; o < 16; o <<= 1) p0 += __shfl_xor(p0, o);
    } else {                 // H=4: head = 32 ch = 4 lanes
      p0 += __shfl_xor(p0, 1);
      p0 += __shfl_xor(p0, 2);
    }
    float e = __expf(p0);
    s += e;
    ac[0] += e * x0.x; ac[1] += e * x0.y; ac[2] += e * x0.z; ac[3] += e * x0.w;
    ac[4] += e * x1.x; ac[5] += e * x1.y; ac[6] += e * x1.z; ac[7] += e * x1.w;
  }
  // combine the four quarter streams (plain sums)
  s += __shfl_xor(s, 16);
  s += __shfl_xor(s, 32);
  #pragma unroll
  for (int j = 0; j < 8; j++) {
    ac[j] += __shfl_xor(ac[j], 16);
    ac[j] += __shfl_xor(ac[j], 32);
  }

  float inv = 1.f / s;
  float ov[8];
  #pragma unroll
  for (int j = 0; j < 8; j++) ov[j] = ac[j] * inv;

  // LayerNorm over 128 (16 lanes of a quarter cover all channels)
  float sum = 0.f, sq = 0.f;
  #pragma unroll
  for (int j = 0; j < 8; j++) { sum += ov[j]; sq += ov[j] * ov[j]; }
  #pragma unroll
  for (int o = 1; o < 16; o <<= 1) {
    sum += __shfl_xor(sum, o);
    sq += __shfl_xor(sq, o);
  }
  float mean = sum * (1.f / 128.f);
  float var = sq * (1.f / 128.f) - mean * mean;
  float rstd = rsqrtf(var + 1e-5f);

  f4v gv0 = *(const f4v*)((const char*)g + cb);
  f4v gv1 = *(const f4v*)((const char*)g + cb + 16);
  f4v bv0 = *(const f4v*)((const char*)b + cb);
  f4v bv1 = *(const f4v*)((const char*)b + cb + 16);
  float gg[8] = {gv0.x, gv0.y, gv0.z, gv0.w, gv1.x, gv1.y, gv1.z, gv1.w};
  float bb[8] = {bv0.x, bv0.y, bv0.z, bv0.w, bv1.x, bv1.y, bv1.z, bv1.w};
  float rv[8];
  #pragma unroll
  for (int j = 0; j < 8; j++) rv[j] = (ov[j] - mean) * rstd * gg[j] + bb[j];
  if (res) {
    const char* rb = (const char*)res + (size_t)row * 512 + cb;
    f4v r0 = __builtin_nontemporal_load((const f4v*)rb);
    f4v r1 = __builtin_nontemporal_load((const f4v*)(rb + 16));
    rv[0] += resScale * r0.x; rv[1] += resScale * r0.y;
    rv[2] += resScale * r0.z; rv[3] += resScale * r0.w;
    rv[4] += resScale * r1.x; rv[5] += resScale * r1.y;
    rv[6] += resScale * r1.z; rv[7] += resScale * r1.w;
  }
  if (doRelu) {
    #pragma unroll
    for (int j = 0; j < 8; j++) rv[j] = fmaxf(rv[j], 0.f);
  }
  if (q == 0) {
    char* yb = (char*)y + (size_t)row * 512 + cb;
    *(f4v*)yb = (f4v){rv[0], rv[1], rv[2], rv[3]};
    *(f4v*)(yb + 16) = (f4v){rv[4], rv[5], rv[6], rv[7]};
  }
}

// ---------- launch ----------
extern "C" void kernel_launch(void* const* d_in, const int* in_sizes, int n_in,
                              void* d_out, int out_size, void* d_ws,
                              size_t ws_size, hipStream_t stream) {
  const float* x       = (const float*)d_in[0];
  const int*   ei      = (const int*)d_in[1];
  const float* ln_in_g = (const float*)d_in[2];
  const float* ln_in_b = (const float*)d_in[3];
  const float* w_l1    = (const float*)d_in[4];
  const float* w_r1    = (const float*)d_in[5];
  const float* att1    = (const float*)d_in[6];
  const float* ln1_g   = (const float*)d_in[7];
  const float* ln1_b   = (const float*)d_in[8];
  const float* w_l2    = (const float*)d_in[9];
  const float* w_r2    = (const float*)d_in[10];
  const float* att2    = (const float*)d_in[11];
  const float* ln2_g   = (const float*)d_in[12];
  const float* ln2_b   = (const float*)d_in[13];
  const float* w_l3    = (const float*)d_in[14];
  const float* w_r3    = (const float*)d_in[15];
  const float* att3    = (const float*)d_in[16];
  const float* ln3_g   = (const float*)d_in[17];
  const float* ln3_b   = (const float*)d_in[18];
  const float* rtt_w1  = (const float*)d_in[19];
  const float* rtt_b1  = (const float*)d_in[20];
  const float* rtt_w2  = (const float*)d_in[21];
  const float* rtt_b2  = (const float*)d_in[22];
  const float* ret_w1  = (const float*)d_in[23];
  const float* ret_b1  = (const float*)d_in[24];
  const float* ret_w2  = (const float*)d_in[25];
  const float* ret_b2  = (const float*)d_in[26];

  const int N = in_sizes[0] / 64;
  const int E = in_sizes[1] / 2;
  const int ET = E + N;
  const size_t NF = (size_t)N * 128;

  float* A = (float*)d_ws;            // node features h / residual
  float* B = A + NF;                  // xl
  float* C = B + NF;                  // xr
  int* deg     = (int*)(C + NF);      // N
  int* rowcur  = deg + N;             // N (row_end after scatter)
  int* incl    = rowcur + N;          // N
  int* bsums   = incl + N;            // 1024
  int* csr_src = bsums + 1024;        // ET
  short* wf = (short*)(((uintptr_t)(csr_src + ET) + 63) & ~(uintptr_t)63);

  float* out = (float*)d_out;

  // segments: wl1, wr1, wl2, wr2, wl3, wr3, rtt_w1, ret_w1
  const int segsz[8] = {64 * 128, 64 * 128, 128 * 128, 128 * 128,
                        128 * 128, 128 * 128, 128 * 64, 128 * 64};
  PrepArgs pa;
  pa.w[0] = w_l1; pa.w[1] = w_r1; pa.w[2] = w_l2; pa.w[3] = w_r2;
  pa.w[4] = w_l3; pa.w[5] = w_r3; pa.w[6] = rtt_w1; pa.w[7] = ret_w1;
  pa.fout[0] = 128; pa.fout[1] = 128; pa.fout[2] = 128; pa.fout[3] = 128;
  pa.fout[4] = 128; pa.fout[5] = 128; pa.fout[6] = 64; pa.fout[7] = 64;
  int acc = 0;
  short* op = wf;
  for (int s = 0; s < 8; s++) {
    pa.cum[s] = acc;
    pa.o[s] = op;
    op += 3 * segsz[s];  // h + m + l planes
    acc += segsz[s];
  }
  pa.cum[8] = acc;

  const int rowBlocks  = (N + 3) / 4;
  const int mmBlocks   = (N + 63) / 64;
  const int NB = (N + 1023) / 1024;

  // ---- W fragment prep ----
  prep_w_kernel<<<(acc + 255) / 256, 256, 0, stream>>>(pa);

  // ---- CSR build (by dst) ----
  fill_ones_kernel<<<(N + 255) / 256, 256, 0, stream>>>(deg, N);
  degree_count_kernel<<<(E + 255) / 256, 256, 0, stream>>>(ei, E, deg);
  scan1_kernel<<<NB, 1024, 0, stream>>>(deg, N, incl, bsums);
  scan2_kernel<<<1, 1024, 0, stream>>>(bsums, NB);
  scan3_kernel<<<NB, 1024, 0, stream>>>(incl, deg, bsums, N, rowcur);
  scatter_kernel<<<(ET + 255) / 256, 256, 0, stream>>>(ei, E, ET, rowcur, csr_src);

  // ---- layer 0: fused LN64 + GEMM 64->128 (L+R), 4 heads, relu ----
  mfma_gemm_ln_lr_kernel<<<mmBlocks, 256, 0, stream>>>(
      x, ln_in_g, ln_in_b, pa.o[0], pa.o[1], B, C, N);
  gat_fused_kernel<4><<<rowBlocks, 256, 0, stream>>>(
      B, C, csr_src, rowcur, deg, att1, nullptr, ln1_g, ln1_b, A, N, 0.f, 1);

  // ---- layer 1: 128 -> 128 (L+R), 4 heads, residual 0.1, relu ----
  mfma_gemm_lr_kernel<<<mmBlocks, 256, 0, stream>>>(A, pa.o[2], pa.o[3], B, C, N);
  gat_fused_kernel<4><<<rowBlocks, 256, 0, stream>>>(
      B, C, csr_src, rowcur, deg, att2, A, ln2_g, ln2_b, A, N, 0.1f, 1);

  // ---- layer 2: 128 -> 128 (L+R), 1 head, residual 0.1, no relu ----
  mfma_gemm_lr_kernel<<<mmBlocks, 256, 0, stream>>>(A, pa.o[4], pa.o[5], B, C, N);
  gat_fused_kernel<1><<<rowBlocks, 256, 0, stream>>>(
      B, C, csr_src, rowcur, deg, att3, A, ln3_g, ln3_b, A, N, 0.1f, 0);

  // ---- prediction heads: both GEMMs + relu + final dots in one dispatch ----
  mfma_head_lr_kernel<<<mmBlocks, 256, 0, stream>>>(
      A, pa.o[6], rtt_b1, rtt_w2, rtt_b2, pa.o[7], ret_b1, ret_w2, ret_b2,
      out, N);
}

// Round 13
// 657.532 us; speedup vs baseline: 1.1347x; 1.0935x over previous
//
#include <hip/hip_runtime.h>
#include <hip/hip_bf16.h>
#include <cstdint>
#include <cstddef>

#define NEG_SLOPE 0.2f

typedef float f4v __attribute__((ext_vector_type(4)));
typedef short short8 __attribute__((ext_vector_type(8)));
typedef float f32x4 __attribute__((ext_vector_type(4)));

// Explicit round-to-nearest-even fp32 -> bf16 (integer form; do NOT trust
// __float2bfloat16 — r12 evidence shows it truncates on this ROCm, leaving
// a BIASED residual ~2^-24*K per dot that the LN chain amplifies to e-3).
__device__ __forceinline__ short rne_bf16(float v) {
  unsigned u = __builtin_bit_cast(unsigned, v);
  u += 0x7FFFu + ((u >> 16) & 1u);
  return (short)(u >> 16);
}
__device__ __forceinline__ float bf16_to_f(short h) {
  unsigned u = ((unsigned)(unsigned short)h) << 16;
  return __builtin_bit_cast(float, u);
}
// fp32 -> 3x bf16, RNE at each level: h=RNE(v), m=RNE(v-h), l=RNE(v-h-m).
// Subtractions exact (Sterbenz). Final residual <= 2^-27|v|, UNBIASED.
// 6-product GEMM {hh,hm,mh,hl,mm,lh}: dropped ml/lm ~2^-27 unbiased ->
// below fp32-GEMM rounding noise.
__device__ __forceinline__ void cvt3(float v, short& h, short& m, short& l) {
  h = rne_bf16(v);
  float r1 = v - bf16_to_f(h);
  m = rne_bf16(r1);
  float r2 = r1 - bf16_to_f(m);
  l = rne_bf16(r2);
}

// ---------- CSR build ----------

__global__ __launch_bounds__(256) void fill_ones_kernel(int* __restrict__ p, int n) {
  int i = blockIdx.x * 256 + threadIdx.x;
  if (i < n) p[i] = 1;  // self-loop contributes degree 1
}

__global__ __launch_bounds__(256) void degree_count_kernel(
    const int* __restrict__ ei, int E, int* __restrict__ deg) {
  int e = blockIdx.x * 256 + threadIdx.x;
  if (e < E) atomicAdd(&deg[ei[E + e]], 1);
}

__global__ __launch_bounds__(1024) void scan1_kernel(
    const int* __restrict__ deg, int n, int* __restrict__ incl,
    int* __restrict__ blocksums) {
  __shared__ int sm[1024];
  int t = threadIdx.x;
  int i = blockIdx.x * 1024 + t;
  sm[t] = (i < n) ? deg[i] : 0;
  __syncthreads();
  #pragma unroll
  for (int o = 1; o < 1024; o <<= 1) {
    int a = (t >= o) ? sm[t - o] : 0;
    __syncthreads();
    sm[t] += a;
    __syncthreads();
  }
  if (i < n) incl[i] = sm[t];
  if (t == 1023) blocksums[blockIdx.x] = sm[t];
}

__global__ __launch_bounds__(1024) void scan2_kernel(int* __restrict__ bs, int nb) {
  __shared__ int sm[1024];
  int t = threadIdx.x;
  sm[t] = (t < nb) ? bs[t] : 0;
  __syncthreads();
  #pragma unroll
  for (int o = 1; o < 1024; o <<= 1) {
    int a = (t >= o) ? sm[t - o] : 0;
    __syncthreads();
    sm[t] += a;
    __syncthreads();
  }
  if (t < nb) bs[t] = sm[t];
}

__global__ __launch_bounds__(1024) void scan3_kernel(
    const int* __restrict__ incl, const int* __restrict__ deg,
    const int* __restrict__ bs, int n, int* __restrict__ rowcur) {
  int i = blockIdx.x * 1024 + threadIdx.x;
  if (i >= n) return;
  int off = (blockIdx.x > 0) ? bs[blockIdx.x - 1] : 0;
  rowcur[i] = incl[i] - deg[i] + off;
}

__global__ __launch_bounds__(256) void scatter_kernel(
    const int* __restrict__ ei, int E, int ET, int* __restrict__ rowcur,
    int* __restrict__ csr_src) {
  int e = blockIdx.x * 256 + threadIdx.x;
  if (e >= ET) return;
  int s, d;
  if (e < E) { s = ei[e]; d = ei[E + e]; }
  else       { s = e - E; d = s; }
  int pos = atomicAdd(&rowcur[d], 1);
  csr_src[pos] = s;
}

// ---------- W -> MFMA B-fragment layout (triple bf16 planes) ----------
struct PrepArgs {
  const float* w[8];
  short* o[8];
  int fout[8];
  int cum[9];
};

__global__ __launch_bounds__(256) void prep_w_kernel(PrepArgs pa) {
  int i = blockIdx.x * 256 + threadIdx.x;
  if (i >= pa.cum[8]) return;
  int s = 0;
  while (i >= pa.cum[s + 1]) s++;
  int li = i - pa.cum[s];
  int FOUT = pa.fout[s];
  int NT = FOUT >> 4;
  int sz = pa.cum[s + 1] - pa.cum[s];
  int c = li / (NT * 512);
  int r1 = li % (NT * 512);
  int t = r1 >> 9;
  int e = r1 & 511;
  int lane = e >> 3, j = e & 7;
  int k = c * 32 + (lane >> 4) * 8 + j;
  int n = t * 16 + (lane & 15);
  float v = pa.w[s][k * FOUT + n];
  short h, m, l;
  cvt3(v, h, m, l);
  pa.o[s][li] = h;
  pa.o[s][li + sz] = m;
  pa.o[s][li + 2 * sz] = l;
}

// 6-term triple-split MFMA accumulate for one tile
#define MFMA6(ah, am, al, bh, bm, bl, acc)                                   \
  acc = __builtin_amdgcn_mfma_f32_16x16x32_bf16(ah, bh, acc, 0, 0, 0);      \
  acc = __builtin_amdgcn_mfma_f32_16x16x32_bf16(ah, bm, acc, 0, 0, 0);      \
  acc = __builtin_amdgcn_mfma_f32_16x16x32_bf16(am, bh, acc, 0, 0, 0);      \
  acc = __builtin_amdgcn_mfma_f32_16x16x32_bf16(ah, bl, acc, 0, 0, 0);      \
  acc = __builtin_amdgcn_mfma_f32_16x16x32_bf16(am, bm, acc, 0, 0, 0);      \
  acc = __builtin_amdgcn_mfma_f32_16x16x32_bf16(al, bh, acc, 0, 0, 0);

// ---------- layer-0 GEMM: fused LN64, 32 rows/wave, y-split L/R ------------
__global__ __launch_bounds__(256, 2) void mfma_gemm_ln_kernel(
    const float* __restrict__ X, const float* __restrict__ lng,
    const float* __restrict__ lnb, const short* __restrict__ WfL,
    const short* __restrict__ WfR, float* __restrict__ YL,
    float* __restrict__ YR, int nrows) {
  constexpr int NT = 8, TOT = 2 * NT * 512;
  const short* Wf = blockIdx.y ? WfR : WfL;
  float* Y = blockIdx.y ? YR : YL;
  const int wave = threadIdx.x >> 6, lane = threadIdx.x & 63;
  const int quad = lane >> 4, ln16 = lane & 15;
  const int rb = blockIdx.x * 128 + wave * 32;
  int r0 = rb + ln16;      int rA0 = r0 < nrows ? r0 : nrows - 1;
  int r1 = rb + 16 + ln16; int rA1 = r1 < nrows ? r1 : nrows - 1;
  const float* xp0 = X + (size_t)rA0 * 64 + quad * 8;
  const float* xp1 = X + (size_t)rA1 * 64 + quad * 8;

  float av0[16], av1[16];
  *(float4*)&av0[0]  = *(const float4*)(xp0);
  *(float4*)&av0[4]  = *(const float4*)(xp0 + 4);
  *(float4*)&av0[8]  = *(const float4*)(xp0 + 32);
  *(float4*)&av0[12] = *(const float4*)(xp0 + 36);
  *(float4*)&av1[0]  = *(const float4*)(xp1);
  *(float4*)&av1[4]  = *(const float4*)(xp1 + 4);
  *(float4*)&av1[8]  = *(const float4*)(xp1 + 32);
  *(float4*)&av1[12] = *(const float4*)(xp1 + 36);

  float s0 = 0.f, q0 = 0.f, s1 = 0.f, q1 = 0.f;
  #pragma unroll
  for (int j = 0; j < 16; j++) {
    s0 += av0[j]; q0 += av0[j] * av0[j];
    s1 += av1[j]; q1 += av1[j] * av1[j];
  }
  s0 += __shfl_xor(s0, 16); s0 += __shfl_xor(s0, 32);
  q0 += __shfl_xor(q0, 16); q0 += __shfl_xor(q0, 32);
  s1 += __shfl_xor(s1, 16); s1 += __shfl_xor(s1, 32);
  q1 += __shfl_xor(q1, 16); q1 += __shfl_xor(q1, 32);
  float mean0 = s0 * (1.f / 64.f);
  float rstd0 = rsqrtf(q0 * (1.f / 64.f) - mean0 * mean0 + 1e-5f);
  float mean1 = s1 * (1.f / 64.f);
  float rstd1 = rsqrtf(q1 * (1.f / 64.f) - mean1 * mean1 + 1e-5f);

  f32x4 acc0[NT], acc1[NT];
  #pragma unroll
  for (int t = 0; t < NT; t++) {
    acc0[t] = (f32x4){0.f, 0.f, 0.f, 0.f};
    acc1[t] = (f32x4){0.f, 0.f, 0.f, 0.f};
  }

  #pragma unroll
  for (int c = 0; c < 2; c++) {
    float4 gv0 = *(const float4*)&lng[quad * 8 + c * 32];
    float4 gv1 = *(const float4*)&lng[quad * 8 + c * 32 + 4];
    float4 bv0 = *(const float4*)&lnb[quad * 8 + c * 32];
    float4 bv1 = *(const float4*)&lnb[quad * 8 + c * 32 + 4];
    float gg[8] = {gv0.x, gv0.y, gv0.z, gv0.w, gv1.x, gv1.y, gv1.z, gv1.w};
    float bb[8] = {bv0.x, bv0.y, bv0.z, bv0.w, bv1.x, bv1.y, bv1.z, bv1.w};
    short8 a0h, a0m, a0l, a1h, a1m, a1l;
    #pragma unroll
    for (int j = 0; j < 8; j++) {
      float v0 = (av0[c * 8 + j] - mean0) * rstd0 * gg[j] + bb[j];
      float v1 = (av1[c * 8 + j] - mean1) * rstd1 * gg[j] + bb[j];
      short h, m, l;
      cvt3(v0, h, m, l); a0h[j] = h; a0m[j] = m; a0l[j] = l;
      cvt3(v1, h, m, l); a1h[j] = h; a1m[j] = m; a1l[j] = l;
    }
    const short* wp = Wf + c * NT * 512 + lane * 8;
    #pragma unroll
    for (int t = 0; t < NT; t++) {
      short8 bh = *(const short8*)(wp + t * 512);
      short8 bm = *(const short8*)(wp + t * 512 + TOT);
      short8 bl = *(const short8*)(wp + t * 512 + 2 * TOT);
      MFMA6(a0h, a0m, a0l, bh, bm, bl, acc0[t]);
      MFMA6(a1h, a1m, a1l, bh, bm, bl, acc1[t]);
    }
  }

  const int rbase = rb + quad * 4;
  #pragma unroll
  for (int t = 0; t < NT; t++)
    #pragma unroll
    for (int r = 0; r < 4; r++) {
      int ra = rbase + r, rbs = rbase + 16 + r;
      if (ra < nrows) Y[(size_t)ra * 128 + t * 16 + ln16] = acc0[t][r];
      if (rbs < nrows) Y[(size_t)rbs * 128 + t * 16 + ln16] = acc1[t][r];
    }
}

// ---------- generic MFMA GEMM: FIN=128, 32 rows/wave, y-split L/R ----------
__global__ __launch_bounds__(256, 2) void mfma_gemm_lr_kernel(
    const float* __restrict__ X, const short* __restrict__ WfL,
    const short* __restrict__ WfR, float* __restrict__ YL,
    float* __restrict__ YR, int nrows) {
  constexpr int NC = 4, NT = 8, TOT = NC * NT * 512;
  const short* Wf = blockIdx.y ? WfR : WfL;
  float* Y = blockIdx.y ? YR : YL;
  const int wave = threadIdx.x >> 6, lane = threadIdx.x & 63;
  const int quad = lane >> 4, ln16 = lane & 15;
  const int rb = blockIdx.x * 128 + wave * 32;
  int r0 = rb + ln16;      int rA0 = r0 < nrows ? r0 : nrows - 1;
  int r1 = rb + 16 + ln16; int rA1 = r1 < nrows ? r1 : nrows - 1;
  const float* xp0 = X + (size_t)rA0 * 128 + quad * 8;
  const float* xp1 = X + (size_t)rA1 * 128 + quad * 8;

  f32x4 acc0[NT], acc1[NT];
  #pragma unroll
  for (int t = 0; t < NT; t++) {
    acc0[t] = (f32x4){0.f, 0.f, 0.f, 0.f};
    acc1[t] = (f32x4){0.f, 0.f, 0.f, 0.f};
  }

  #pragma unroll
  for (int c = 0; c < NC; c++) {
    float4 x00 = *(const float4*)(xp0 + c * 32);
    float4 x01 = *(const float4*)(xp0 + c * 32 + 4);
    float4 x10 = *(const float4*)(xp1 + c * 32);
    float4 x11 = *(const float4*)(xp1 + c * 32 + 4);
    float a0[8] = {x00.x, x00.y, x00.z, x00.w, x01.x, x01.y, x01.z, x01.w};
    float a1[8] = {x10.x, x10.y, x10.z, x10.w, x11.x, x11.y, x11.z, x11.w};
    short8 a0h, a0m, a0l, a1h, a1m, a1l;
    #pragma unroll
    for (int j = 0; j < 8; j++) {
      short h, m, l;
      cvt3(a0[j], h, m, l); a0h[j] = h; a0m[j] = m; a0l[j] = l;
      cvt3(a1[j], h, m, l); a1h[j] = h; a1m[j] = m; a1l[j] = l;
    }
    const short* wp = Wf + c * NT * 512 + lane * 8;
    #pragma unroll
    for (int t = 0; t < NT; t++) {
      short8 bh = *(const short8*)(wp + t * 512);
      short8 bm = *(const short8*)(wp + t * 512 + TOT);
      short8 bl = *(const short8*)(wp + t * 512 + 2 * TOT);
      MFMA6(a0h, a0m, a0l, bh, bm, bl, acc0[t]);
      MFMA6(a1h, a1m, a1l, bh, bm, bl, acc1[t]);
    }
  }

  const int rbase = rb + quad * 4;
  #pragma unroll
  for (int t = 0; t < NT; t++)
    #pragma unroll
    for (int r = 0; r < 4; r++) {
      int ra = rbase + r, rbs = rbase + 16 + r;
      if (ra < nrows) Y[(size_t)ra * 128 + t * 16 + ln16] = acc0[t][r];
      if (rbs < nrows) Y[(size_t)rbs * 128 + t * 16 + ln16] = acc1[t][r];
    }
}

// ---------- head GEMMs fused with final dots: out[row,0..1] in one block ---
__global__ __launch_bounds__(256, 2) void mfma_head_lr_kernel(
    const float* __restrict__ X, const short* __restrict__ Wf1,
    const float* __restrict__ b1a, const float* __restrict__ w2a,
    const float* __restrict__ b2a, const short* __restrict__ Wf2,
    const float* __restrict__ b1b, const float* __restrict__ w2b,
    const float* __restrict__ b2b, float* __restrict__ out, int nrows) {
  constexpr int NC = 4, NT = 4, TOT = NC * NT * 512;
  const int wave = threadIdx.x >> 6, lane = threadIdx.x & 63;
  const int quad = lane >> 4, ln16 = lane & 15;
  int rowA = blockIdx.x * 64 + wave * 16 + ln16;
  int rA = rowA < nrows ? rowA : nrows - 1;
  const float* xp = X + (size_t)rA * 128 + quad * 8;

  f32x4 accL[NT], accR[NT];
  #pragma unroll
  for (int t = 0; t < NT; t++) {
    accL[t] = (f32x4){0.f, 0.f, 0.f, 0.f};
    accR[t] = (f32x4){0.f, 0.f, 0.f, 0.f};
  }

  #pragma unroll
  for (int c = 0; c < NC; c++) {
    float4 a0 = *(const float4*)(xp + c * 32);
    float4 a1 = *(const float4*)(xp + c * 32 + 4);
    float av[8] = {a0.x, a0.y, a0.z, a0.w, a1.x, a1.y, a1.z, a1.w};
    short8 ah, am, al;
    #pragma unroll
    for (int j = 0; j < 8; j++) {
      short h, m, l;
      cvt3(av[j], h, m, l);
      ah[j] = h; am[j] = m; al[j] = l;
    }
    const short* wpL = Wf1 + c * NT * 512 + lane * 8;
    const short* wpR = Wf2 + c * NT * 512 + lane * 8;
    #pragma unroll
    for (int t = 0; t < NT; t++) {
      short8 bh = *(const short8*)(wpL + t * 512);
      short8 bm = *(const short8*)(wpL + t * 512 + TOT);
      short8 bl = *(const short8*)(wpL + t * 512 + 2 * TOT);
      MFMA6(ah, am, al, bh, bm, bl, accL[t]);
      short8 ch = *(const short8*)(wpR + t * 512);
      short8 cm = *(const short8*)(wpR + t * 512 + TOT);
      short8 cl = *(const short8*)(wpR + t * 512 + 2 * TOT);
      MFMA6(ah, am, al, ch, cm, cl, accR[t]);
    }
  }

  float prA[4] = {0.f, 0.f, 0.f, 0.f};
  float prB[4] = {0.f, 0.f, 0.f, 0.f};
  #pragma unroll
  for (int t = 0; t < NT; t++) {
    float bvA = b1a[t * 16 + ln16], wvA = w2a[t * 16 + ln16];
    float bvB = b1b[t * 16 + ln16], wvB = w2b[t * 16 + ln16];
    #pragma unroll
    for (int r = 0; r < 4; r++) {
      prA[r] += fmaxf(accL[t][r] + bvA, 0.f) * wvA;
      prB[r] += fmaxf(accR[t][r] + bvB, 0.f) * wvB;
    }
  }
  #pragma unroll
  for (int o = 1; o < 16; o <<= 1)
    #pragma unroll
    for (int r = 0; r < 4; r++) {
      prA[r] += __shfl_xor(prA[r], o);
      prB[r] += __shfl_xor(prB[r], o);
    }
  if (ln16 == 0) {
    const float bb2a = b2a[0], bb2b = b2b[0];
    const int rbase = blockIdx.x * 64 + wave * 16 + quad * 4;
    #pragma unroll
    for (int r = 0; r < 4; r++) {
      int rr = rbase + r;
      if (rr < nrows) {
        out[(size_t)rr * 2 + 0] = prA[r] + bb2a;
        out[(size_t)rr * 2 + 1] = prB[r] + bb2b;
      }
    }
  }
}

// ---------- fused GAT layer -------------------------------------------------
template <int H>
__global__ __launch_bounds__(256) void gat_fused_kernel(
    const float* __restrict__ xl, const float* __restrict__ xr,
    const int* __restrict__ csr_src, const int* __restrict__ row_end,
    const int* __restrict__ deg, const float* __restrict__ att,
    const float* __restrict__ res, const float* __restrict__ g,
    const float* __restrict__ b, float* __restrict__ y, int n,
    float resScale, int doRelu) {
  int row = blockIdx.x * 4 + (threadIdx.x >> 6);
  if (row >= n) return;
  int l = threadIdx.x & 63;
  int q = l >> 4;
  int ln = l & 15;
  int cb = ln * 32;  // byte offset of lane's 8-channel chunk
  int end = row_end[row];
  int dg = deg[row];
  int start = end - dg;
  int cnt = (dg - q + 3) >> 2;  // edges for this quarter (dg >= 1 always)

  const char* xrb = (const char*)xr + (size_t)row * 512 + cb;
  f4v xr0 = __builtin_nontemporal_load((const f4v*)xrb);
  f4v xr1 = __builtin_nontemporal_load((const f4v*)(xrb + 16));
  f4v av0 = *(const f4v*)((const char*)att + cb);
  f4v av1 = *(const f4v*)((const char*)att + cb + 16);

  float s = 0.f;
  float ac[8] = {0.f, 0.f, 0.f, 0.f, 0.f, 0.f, 0.f, 0.f};

  int idx = start + q;
  f4v xn0 = {0.f, 0.f, 0.f, 0.f}, xn1 = {0.f, 0.f, 0.f, 0.f};
  if (cnt > 0) {
    const char* p = (const char*)xl + (size_t)csr_src[idx] * 512 + cb;
    xn0 = *(const f4v*)p;
    xn1 = *(const f4v*)(p + 16);
  }
  for (int i = 0; i < cnt; i++) {
    f4v x0 = xn0, x1 = xn1;
    if (i + 1 < cnt) {
      const char* p = (const char*)xl + (size_t)csr_src[idx + 4] * 512 + cb;
      xn0 = *(const f4v*)p;
      xn1 = *(const f4v*)(p + 16);
    }
    idx += 4;
    float p0;
    {
      float t0 = x0.x + xr0.x, t1 = x0.y + xr0.y;
      float t2 = x0.z + xr0.z, t3 = x0.w + xr0.w;
      float t4 = x1.x + xr1.x, t5 = x1.y + xr1.y;
      float t6 = x1.z + xr1.z, t7 = x1.w + xr1.w;
      float v0 = fmaxf(t0, NEG_SLOPE * t0), v1 = fmaxf(t1, NEG_SLOPE * t1);
      float v2 = fmaxf(t2, NEG_SLOPE * t2), v3 = fmaxf(t3, NEG_SLOPE * t3);
      float v4 = fmaxf(t4, NEG_SLOPE * t4), v5 = fmaxf(t5, NEG_SLOPE * t5);
      float v6 = fmaxf(t6, NEG_SLOPE * t6), v7 = fmaxf(t7, NEG_SLOPE * t7);
      p0 = v0 * av0.x + v1 * av0.y + v2 * av0.z + v3 * av0.w +
           v4 * av1.x + v5 * av1.y + v6 * av1.z + v7 * av1.w;
    }
    if constexpr (H == 1) {  // logit over 128 ch = 16 lanes
      #pragma unroll
      for (int o = 1; o < 16; o <<= 1) p0 += __shfl_xor(p0, o);
    } else {                 // H=4: head = 32 ch = 4 lanes
      p0 += __shfl_xor(p0, 1);
      p0 += __shfl_xor(p0, 2);
    }
    float e = __expf(p0);
    s += e;
    ac[0] += e * x0.x; ac[1] += e * x0.y; ac[2] += e * x0.z; ac[3] += e * x0.w;
    ac[4] += e * x1.x; ac[5] += e * x1.y; ac[6] += e * x1.z; ac[7] += e * x1.w;
  }
  // combine the four quarter streams (plain sums)
  s += __shfl_xor(s, 16);
  s += __shfl_xor(s, 32);
  #pragma unroll
  for (int j = 0; j < 8; j++) {
    ac[j] += __shfl_xor(ac[j], 16);
    ac[j] += __shfl_xor(ac[j], 32);
  }

  float inv = 1.f / s;
  float ov[8];
  #pragma unroll
  for (int j = 0; j < 8; j++) ov[j] = ac[j] * inv;

  // LayerNorm over 128 (16 lanes of a quarter cover all channels)
  float sum = 0.f, sq = 0.f;
  #pragma unroll
  for (int j = 0; j < 8; j++) { sum += ov[j]; sq += ov[j] * ov[j]; }
  #pragma unroll
  for (int o = 1; o < 16; o <<= 1) {
    sum += __shfl_xor(sum, o);
    sq += __shfl_xor(sq, o);
  }
  float mean = sum * (1.f / 128.f);
  float var = sq * (1.f / 128.f) - mean * mean;
  float rstd = rsqrtf(var + 1e-5f);

  f4v gv0 = *(const f4v*)((const char*)g + cb);
  f4v gv1 = *(const f4v*)((const char*)g + cb + 16);
  f4v bv0 = *(const f4v*)((const char*)b + cb);
  f4v bv1 = *(const f4v*)((const char*)b + cb + 16);
  float gg[8] = {gv0.x, gv0.y, gv0.z, gv0.w, gv1.x, gv1.y, gv1.z, gv1.w};
  float bb[8] = {bv0.x, bv0.y, bv0.z, bv0.w, bv1.x, bv1.y, bv1.z, bv1.w};
  float rv[8];
  #pragma unroll
  for (int j = 0; j < 8; j++) rv[j] = (ov[j] - mean) * rstd * gg[j] + bb[j];
  if (res) {
    const char* rb = (const char*)res + (size_t)row * 512 + cb;
    f4v r0 = __builtin_nontemporal_load((const f4v*)rb);
    f4v r1 = __builtin_nontemporal_load((const f4v*)(rb + 16));
    rv[0] += resScale * r0.x; rv[1] += resScale * r0.y;
    rv[2] += resScale * r0.z; rv[3] += resScale * r0.w;
    rv[4] += resScale * r1.x; rv[5] += resScale * r1.y;
    rv[6] += resScale * r1.z; rv[7] += resScale * r1.w;
  }
  if (doRelu) {
    #pragma unroll
    for (int j = 0; j < 8; j++) rv[j] = fmaxf(rv[j], 0.f);
  }
  if (q == 0) {
    char* yb = (char*)y + (size_t)row * 512 + cb;
    *(f4v*)yb = (f4v){rv[0], rv[1], rv[2], rv[3]};
    *(f4v*)(yb + 16) = (f4v){rv[4], rv[5], rv[6], rv[7]};
  }
}

// ---------- launch ----------
extern "C" void kernel_launch(void* const* d_in, const int* in_sizes, int n_in,
                              void* d_out, int out_size, void* d_ws,
                              size_t ws_size, hipStream_t stream) {
  const float* x       = (const float*)d_in[0];
  const int*   ei      = (const int*)d_in[1];
  const float* ln_in_g = (const float*)d_in[2];
  const float* ln_in_b = (const float*)d_in[3];
  const float* w_l1    = (const float*)d_in[4];
  const float* w_r1    = (const float*)d_in[5];
  const float* att1    = (const float*)d_in[6];
  const float* ln1_g   = (const float*)d_in[7];
  const float* ln1_b   = (const float*)d_in[8];
  const float* w_l2    = (const float*)d_in[9];
  const float* w_r2    = (const float*)d_in[10];
  const float* att2    = (const float*)d_in[11];
  const float* ln2_g   = (const float*)d_in[12];
  const float* ln2_b   = (const float*)d_in[13];
  const float* w_l3    = (const float*)d_in[14];
  const float* w_r3    = (const float*)d_in[15];
  const float* att3    = (const float*)d_in[16];
  const float* ln3_g   = (const float*)d_in[17];
  const float* ln3_b   = (const float*)d_in[18];
  const float* rtt_w1  = (const float*)d_in[19];
  const float* rtt_b1  = (const float*)d_in[20];
  const float* rtt_w2  = (const float*)d_in[21];
  const float* rtt_b2  = (const float*)d_in[22];
  const float* ret_w1  = (const float*)d_in[23];
  const float* ret_b1  = (const float*)d_in[24];
  const float* ret_w2  = (const float*)d_in[25];
  const float* ret_b2  = (const float*)d_in[26];

  const int N = in_sizes[0] / 64;
  const int E = in_sizes[1] / 2;
  const int ET = E + N;
  const size_t NF = (size_t)N * 128;

  float* A = (float*)d_ws;            // node features h / residual
  float* B = A + NF;                  // xl
  float* C = B + NF;                  // xr
  int* deg     = (int*)(C + NF);      // N
  int* rowcur  = deg + N;             // N (row_end after scatter)
  int* incl    = rowcur + N;          // N
  int* bsums   = incl + N;            // 1024
  int* csr_src = bsums + 1024;        // ET
  short* wf = (short*)(((uintptr_t)(csr_src + ET) + 63) & ~(uintptr_t)63);

  float* out = (float*)d_out;

  // segments: wl1, wr1, wl2, wr2, wl3, wr3, rtt_w1, ret_w1
  const int segsz[8] = {64 * 128, 64 * 128, 128 * 128, 128 * 128,
                        128 * 128, 128 * 128, 128 * 64, 128 * 64};
  PrepArgs pa;
  pa.w[0] = w_l1; pa.w[1] = w_r1; pa.w[2] = w_l2; pa.w[3] = w_r2;
  pa.w[4] = w_l3; pa.w[5] = w_r3; pa.w[6] = rtt_w1; pa.w[7] = ret_w1;
  pa.fout[0] = 128; pa.fout[1] = 128; pa.fout[2] = 128; pa.fout[3] = 128;
  pa.fout[4] = 128; pa.fout[5] = 128; pa.fout[6] = 64; pa.fout[7] = 64;
  int acc = 0;
  short* op = wf;
  for (int s = 0; s < 8; s++) {
    pa.cum[s] = acc;
    pa.o[s] = op;
    op += 3 * segsz[s];  // h + m + l planes
    acc += segsz[s];
  }
  pa.cum[8] = acc;

  const int rowBlocks  = (N + 3) / 4;
  const int mmBlocks   = (N + 63) / 64;    // head kernel: 64 rows/block
  const int mmBlocks2  = (N + 127) / 128;  // 32-row-wave GEMMs: 128 rows/block
  const int NB = (N + 1023) / 1024;
  dim3 lrGrid(mmBlocks2, 2);

  // ---- W fragment prep ----
  prep_w_kernel<<<(acc + 255) / 256, 256, 0, stream>>>(pa);

  // ---- CSR build (by dst) ----
  fill_ones_kernel<<<(N + 255) / 256, 256, 0, stream>>>(deg, N);
  degree_count_kernel<<<(E + 255) / 256, 256, 0, stream>>>(ei, E, deg);
  scan1_kernel<<<NB, 1024, 0, stream>>>(deg, N, incl, bsums);
  scan2_kernel<<<1, 1024, 0, stream>>>(bsums, NB);
  scan3_kernel<<<NB, 1024, 0, stream>>>(incl, deg, bsums, N, rowcur);
  scatter_kernel<<<(ET + 255) / 256, 256, 0, stream>>>(ei, E, ET, rowcur, csr_src);

  // ---- layer 0: fused LN64 + GEMM 64->128 (y-split L/R), 4 heads, relu ----
  mfma_gemm_ln_kernel<<<lrGrid, 256, 0, stream>>>(
      x, ln_in_g, ln_in_b, pa.o[0], pa.o[1], B, C, N);
  gat_fused_kernel<4><<<rowBlocks, 256, 0, stream>>>(
      B, C, csr_src, rowcur, deg, att1, nullptr, ln1_g, ln1_b, A, N, 0.f, 1);

  // ---- layer 1: 128 -> 128 (y-split L/R), 4 heads, residual 0.1, relu ----
  mfma_gemm_lr_kernel<<<lrGrid, 256, 0, stream>>>(A, pa.o[2], pa.o[3], B, C, N);
  gat_fused_kernel<4><<<rowBlocks, 256, 0, stream>>>(
      B, C, csr_src, rowcur, deg, att2, A, ln2_g, ln2_b, A, N, 0.1f, 1);

  // ---- layer 2: 128 -> 128 (y-split L/R), 1 head, residual 0.1, no relu ----
  mfma_gemm_lr_kernel<<<lrGrid, 256, 0, stream>>>(A, pa.o[4], pa.o[5], B, C, N);
  gat_fused_kernel<1><<<rowBlocks, 256, 0, stream>>>(
      B, C, csr_src, rowcur, deg, att3, A, ln3_g, ln3_b, A, N, 0.1f, 0);

  // ---- prediction heads: both GEMMs + relu + final dots in one dispatch ----
  mfma_head_lr_kernel<<<mmBlocks, 256, 0, stream>>>(
      A, pa.o[6], rtt_b1, rtt_w2, rtt_b2, pa.o[7], ret_b1, ret_w2, ret_b2,
      out, N);
}

// Round 14
// 653.893 us; speedup vs baseline: 1.1410x; 1.0056x over previous
//
#include <hip/hip_runtime.h>
#include <hip/hip_bf16.h>
#include <cstdint>
#include <cstddef>

#define NEG_SLOPE 0.2f

typedef float f4v __attribute__((ext_vector_type(4)));
typedef short short8 __attribute__((ext_vector_type(8)));
typedef float f32x4 __attribute__((ext_vector_type(4)));

// Explicit round-to-nearest-even fp32 -> bf16 (integer form; r12 evidence:
// __float2bfloat16 truncates on this ROCm -> biased residual -> e-3 scatter).
__device__ __forceinline__ short rne_bf16(float v) {
  unsigned u = __builtin_bit_cast(unsigned, v);
  u += 0x7FFFu + ((u >> 16) & 1u);
  return (short)(u >> 16);
}
__device__ __forceinline__ float bf16_to_f(short h) {
  unsigned u = ((unsigned)(unsigned short)h) << 16;
  return __builtin_bit_cast(float, u);
}
// fp32 -> 3x bf16, RNE at each level. Residual <= 2^-27|v|, unbiased.
__device__ __forceinline__ void cvt3(float v, short& h, short& m, short& l) {
  h = rne_bf16(v);
  float r1 = v - bf16_to_f(h);
  m = rne_bf16(r1);
  float r2 = r1 - bf16_to_f(m);
  l = rne_bf16(r2);
}

// ---------- CSR build ----------

__global__ __launch_bounds__(256) void fill_ones_kernel(int* __restrict__ p, int n) {
  int i = blockIdx.x * 256 + threadIdx.x;
  if (i < n) p[i] = 1;  // self-loop contributes degree 1
}

__global__ __launch_bounds__(256) void degree_count_kernel(
    const int* __restrict__ ei, int E, int* __restrict__ deg) {
  int e = blockIdx.x * 256 + threadIdx.x;
  if (e < E) atomicAdd(&deg[ei[E + e]], 1);
}

__global__ __launch_bounds__(1024) void scan1_kernel(
    const int* __restrict__ deg, int n, int* __restrict__ incl,
    int* __restrict__ blocksums) {
  __shared__ int sm[1024];
  int t = threadIdx.x;
  int i = blockIdx.x * 1024 + t;
  sm[t] = (i < n) ? deg[i] : 0;
  __syncthreads();
  #pragma unroll
  for (int o = 1; o < 1024; o <<= 1) {
    int a = (t >= o) ? sm[t - o] : 0;
    __syncthreads();
    sm[t] += a;
    __syncthreads();
  }
  if (i < n) incl[i] = sm[t];
  if (t == 1023) blocksums[blockIdx.x] = sm[t];
}

__global__ __launch_bounds__(1024) void scan2_kernel(int* __restrict__ bs, int nb) {
  __shared__ int sm[1024];
  int t = threadIdx.x;
  sm[t] = (t < nb) ? bs[t] : 0;
  __syncthreads();
  #pragma unroll
  for (int o = 1; o < 1024; o <<= 1) {
    int a = (t >= o) ? sm[t - o] : 0;
    __syncthreads();
    sm[t] += a;
    __syncthreads();
  }
  if (t < nb) bs[t] = sm[t];
}

__global__ __launch_bounds__(1024) void scan3_kernel(
    const int* __restrict__ incl, const int* __restrict__ deg,
    const int* __restrict__ bs, int n, int* __restrict__ rowcur) {
  int i = blockIdx.x * 1024 + threadIdx.x;
  if (i >= n) return;
  int off = (blockIdx.x > 0) ? bs[blockIdx.x - 1] : 0;
  rowcur[i] = incl[i] - deg[i] + off;
}

__global__ __launch_bounds__(256) void scatter_kernel(
    const int* __restrict__ ei, int E, int ET, int* __restrict__ rowcur,
    int* __restrict__ csr_src) {
  int e = blockIdx.x * 256 + threadIdx.x;
  if (e >= ET) return;
  int s, d;
  if (e < E) { s = ei[e]; d = ei[E + e]; }
  else       { s = e - E; d = s; }
  int pos = atomicAdd(&rowcur[d], 1);
  csr_src[pos] = s;
}

// ---------- W -> MFMA B-fragment layout (triple bf16 planes) ----------
struct PrepArgs {
  const float* w[8];
  short* o[8];
  int fout[8];
  int cum[9];
};

__global__ __launch_bounds__(256) void prep_w_kernel(PrepArgs pa) {
  int i = blockIdx.x * 256 + threadIdx.x;
  if (i >= pa.cum[8]) return;
  int s = 0;
  while (i >= pa.cum[s + 1]) s++;
  int li = i - pa.cum[s];
  int FOUT = pa.fout[s];
  int NT = FOUT >> 4;
  int sz = pa.cum[s + 1] - pa.cum[s];
  int c = li / (NT * 512);
  int r1 = li % (NT * 512);
  int t = r1 >> 9;
  int e = r1 & 511;
  int lane = e >> 3, j = e & 7;
  int k = c * 32 + (lane >> 4) * 8 + j;
  int n = t * 16 + (lane & 15);
  float v = pa.w[s][k * FOUT + n];
  short h, m, l;
  cvt3(v, h, m, l);
  pa.o[s][li] = h;
  pa.o[s][li + sz] = m;
  pa.o[s][li + 2 * sz] = l;
}

// 6-term triple-split MFMA accumulate for one tile
#define MFMA6(ah, am, al, bh, bm, bl, acc)                                   \
  acc = __builtin_amdgcn_mfma_f32_16x16x32_bf16(ah, bh, acc, 0, 0, 0);      \
  acc = __builtin_amdgcn_mfma_f32_16x16x32_bf16(ah, bm, acc, 0, 0, 0);      \
  acc = __builtin_amdgcn_mfma_f32_16x16x32_bf16(am, bh, acc, 0, 0, 0);      \
  acc = __builtin_amdgcn_mfma_f32_16x16x32_bf16(ah, bl, acc, 0, 0, 0);      \
  acc = __builtin_amdgcn_mfma_f32_16x16x32_bf16(am, bm, acc, 0, 0, 0);      \
  acc = __builtin_amdgcn_mfma_f32_16x16x32_bf16(al, bh, acc, 0, 0, 0);

// ---------- layer-0 GEMM: fused LN64, 32 rows/wave, y-split L/R ------------
__global__ __launch_bounds__(256, 2) void mfma_gemm_ln_kernel(
    const float* __restrict__ X, const float* __restrict__ lng,
    const float* __restrict__ lnb, const short* __restrict__ WfL,
    const short* __restrict__ WfR, float* __restrict__ YL,
    float* __restrict__ YR, int nrows) {
  constexpr int NT = 8, TOT = 2 * NT * 512;
  const short* Wf = blockIdx.y ? WfR : WfL;
  float* Y = blockIdx.y ? YR : YL;
  const int wave = threadIdx.x >> 6, lane = threadIdx.x & 63;
  const int quad = lane >> 4, ln16 = lane & 15;
  const int rb = blockIdx.x * 128 + wave * 32;
  int r0 = rb + ln16;      int rA0 = r0 < nrows ? r0 : nrows - 1;
  int r1 = rb + 16 + ln16; int rA1 = r1 < nrows ? r1 : nrows - 1;
  const float* xp0 = X + (size_t)rA0 * 64 + quad * 8;
  const float* xp1 = X + (size_t)rA1 * 64 + quad * 8;

  float av0[16], av1[16];
  *(float4*)&av0[0]  = *(const float4*)(xp0);
  *(float4*)&av0[4]  = *(const float4*)(xp0 + 4);
  *(float4*)&av0[8]  = *(const float4*)(xp0 + 32);
  *(float4*)&av0[12] = *(const float4*)(xp0 + 36);
  *(float4*)&av1[0]  = *(const float4*)(xp1);
  *(float4*)&av1[4]  = *(const float4*)(xp1 + 4);
  *(float4*)&av1[8]  = *(const float4*)(xp1 + 32);
  *(float4*)&av1[12] = *(const float4*)(xp1 + 36);

  float s0 = 0.f, q0 = 0.f, s1 = 0.f, q1 = 0.f;
  #pragma unroll
  for (int j = 0; j < 16; j++) {
    s0 += av0[j]; q0 += av0[j] * av0[j];
    s1 += av1[j]; q1 += av1[j] * av1[j];
  }
  s0 += __shfl_xor(s0, 16); s0 += __shfl_xor(s0, 32);
  q0 += __shfl_xor(q0, 16); q0 += __shfl_xor(q0, 32);
  s1 += __shfl_xor(s1, 16); s1 += __shfl_xor(s1, 32);
  q1 += __shfl_xor(q1, 16); q1 += __shfl_xor(q1, 32);
  float mean0 = s0 * (1.f / 64.f);
  float rstd0 = rsqrtf(q0 * (1.f / 64.f) - mean0 * mean0 + 1e-5f);
  float mean1 = s1 * (1.f / 64.f);
  float rstd1 = rsqrtf(q1 * (1.f / 64.f) - mean1 * mean1 + 1e-5f);

  f32x4 acc0[NT], acc1[NT];
  #pragma unroll
  for (int t = 0; t < NT; t++) {
    acc0[t] = (f32x4){0.f, 0.f, 0.f, 0.f};
    acc1[t] = (f32x4){0.f, 0.f, 0.f, 0.f};
  }

  #pragma unroll
  for (int c = 0; c < 2; c++) {
    float4 gv0 = *(const float4*)&lng[quad * 8 + c * 32];
    float4 gv1 = *(const float4*)&lng[quad * 8 + c * 32 + 4];
    float4 bv0 = *(const float4*)&lnb[quad * 8 + c * 32];
    float4 bv1 = *(const float4*)&lnb[quad * 8 + c * 32 + 4];
    float gg[8] = {gv0.x, gv0.y, gv0.z, gv0.w, gv1.x, gv1.y, gv1.z, gv1.w};
    float bb[8] = {bv0.x, bv0.y, bv0.z, bv0.w, bv1.x, bv1.y, bv1.z, bv1.w};
    short8 a0h, a0m, a0l, a1h, a1m, a1l;
    #pragma unroll
    for (int j = 0; j < 8; j++) {
      float v0 = (av0[c * 8 + j] - mean0) * rstd0 * gg[j] + bb[j];
      float v1 = (av1[c * 8 + j] - mean1) * rstd1 * gg[j] + bb[j];
      short h, m, l;
      cvt3(v0, h, m, l); a0h[j] = h; a0m[j] = m; a0l[j] = l;
      cvt3(v1, h, m, l); a1h[j] = h; a1m[j] = m; a1l[j] = l;
    }
    const short* wp = Wf + c * NT * 512 + lane * 8;
    #pragma unroll
    for (int t = 0; t < NT; t++) {
      short8 bh = *(const short8*)(wp + t * 512);
      short8 bm = *(const short8*)(wp + t * 512 + TOT);
      short8 bl = *(const short8*)(wp + t * 512 + 2 * TOT);
      MFMA6(a0h, a0m, a0l, bh, bm, bl, acc0[t]);
      MFMA6(a1h, a1m, a1l, bh, bm, bl, acc1[t]);
    }
  }

  const int rbase = rb + quad * 4;
  #pragma unroll
  for (int t = 0; t < NT; t++)
    #pragma unroll
    for (int r = 0; r < 4; r++) {
      int ra = rbase + r, rbs = rbase + 16 + r;
      if (ra < nrows) Y[(size_t)ra * 128 + t * 16 + ln16] = acc0[t][r];
      if (rbs < nrows) Y[(size_t)rbs * 128 + t * 16 + ln16] = acc1[t][r];
    }
}

// ---------- generic MFMA GEMM: FIN=128, 32 rows/wave, y-split L/R ----------
__global__ __launch_bounds__(256, 2) void mfma_gemm_lr_kernel(
    const float* __restrict__ X, const short* __restrict__ WfL,
    const short* __restrict__ WfR, float* __restrict__ YL,
    float* __restrict__ YR, int nrows) {
  constexpr int NC = 4, NT = 8, TOT = NC * NT * 512;
  const short* Wf = blockIdx.y ? WfR : WfL;
  float* Y = blockIdx.y ? YR : YL;
  const int wave = threadIdx.x >> 6, lane = threadIdx.x & 63;
  const int quad = lane >> 4, ln16 = lane & 15;
  const int rb = blockIdx.x * 128 + wave * 32;
  int r0 = rb + ln16;      int rA0 = r0 < nrows ? r0 : nrows - 1;
  int r1 = rb + 16 + ln16; int rA1 = r1 < nrows ? r1 : nrows - 1;
  const float* xp0 = X + (size_t)rA0 * 128 + quad * 8;
  const float* xp1 = X + (size_t)rA1 * 128 + quad * 8;

  f32x4 acc0[NT], acc1[NT];
  #pragma unroll
  for (int t = 0; t < NT; t++) {
    acc0[t] = (f32x4){0.f, 0.f, 0.f, 0.f};
    acc1[t] = (f32x4){0.f, 0.f, 0.f, 0.f};
  }

  #pragma unroll
  for (int c = 0; c < NC; c++) {
    float4 x00 = *(const float4*)(xp0 + c * 32);
    float4 x01 = *(const float4*)(xp0 + c * 32 + 4);
    float4 x10 = *(const float4*)(xp1 + c * 32);
    float4 x11 = *(const float4*)(xp1 + c * 32 + 4);
    float a0[8] = {x00.x, x00.y, x00.z, x00.w, x01.x, x01.y, x01.z, x01.w};
    float a1[8] = {x10.x, x10.y, x10.z, x10.w, x11.x, x11.y, x11.z, x11.w};
    short8 a0h, a0m, a0l, a1h, a1m, a1l;
    #pragma unroll
    for (int j = 0; j < 8; j++) {
      short h, m, l;
      cvt3(a0[j], h, m, l); a0h[j] = h; a0m[j] = m; a0l[j] = l;
      cvt3(a1[j], h, m, l); a1h[j] = h; a1m[j] = m; a1l[j] = l;
    }
    const short* wp = Wf + c * NT * 512 + lane * 8;
    #pragma unroll
    for (int t = 0; t < NT; t++) {
      short8 bh = *(const short8*)(wp + t * 512);
      short8 bm = *(const short8*)(wp + t * 512 + TOT);
      short8 bl = *(const short8*)(wp + t * 512 + 2 * TOT);
      MFMA6(a0h, a0m, a0l, bh, bm, bl, acc0[t]);
      MFMA6(a1h, a1m, a1l, bh, bm, bl, acc1[t]);
    }
  }

  const int rbase = rb + quad * 4;
  #pragma unroll
  for (int t = 0; t < NT; t++)
    #pragma unroll
    for (int r = 0; r < 4; r++) {
      int ra = rbase + r, rbs = rbase + 16 + r;
      if (ra < nrows) Y[(size_t)ra * 128 + t * 16 + ln16] = acc0[t][r];
      if (rbs < nrows) Y[(size_t)rbs * 128 + t * 16 + ln16] = acc1[t][r];
    }
}

// ---------- head GEMMs fused with final dots: out[row,0..1] in one block ---
__global__ __launch_bounds__(256, 2) void mfma_head_lr_kernel(
    const float* __restrict__ X, const short* __restrict__ Wf1,
    const float* __restrict__ b1a, const float* __restrict__ w2a,
    const float* __restrict__ b2a, const short* __restrict__ Wf2,
    const float* __restrict__ b1b, const float* __restrict__ w2b,
    const float* __restrict__ b2b, float* __restrict__ out, int nrows) {
  constexpr int NC = 4, NT = 4, TOT = NC * NT * 512;
  const int wave = threadIdx.x >> 6, lane = threadIdx.x & 63;
  const int quad = lane >> 4, ln16 = lane & 15;
  int rowA = blockIdx.x * 64 + wave * 16 + ln16;
  int rA = rowA < nrows ? rowA : nrows - 1;
  const float* xp = X + (size_t)rA * 128 + quad * 8;

  f32x4 accL[NT], accR[NT];
  #pragma unroll
  for (int t = 0; t < NT; t++) {
    accL[t] = (f32x4){0.f, 0.f, 0.f, 0.f};
    accR[t] = (f32x4){0.f, 0.f, 0.f, 0.f};
  }

  #pragma unroll
  for (int c = 0; c < NC; c++) {
    float4 a0 = *(const float4*)(xp + c * 32);
    float4 a1 = *(const float4*)(xp + c * 32 + 4);
    float av[8] = {a0.x, a0.y, a0.z, a0.w, a1.x, a1.y, a1.z, a1.w};
    short8 ah, am, al;
    #pragma unroll
    for (int j = 0; j < 8; j++) {
      short h, m, l;
      cvt3(av[j], h, m, l);
      ah[j] = h; am[j] = m; al[j] = l;
    }
    const short* wpL = Wf1 + c * NT * 512 + lane * 8;
    const short* wpR = Wf2 + c * NT * 512 + lane * 8;
    #pragma unroll
    for (int t = 0; t < NT; t++) {
      short8 bh = *(const short8*)(wpL + t * 512);
      short8 bm = *(const short8*)(wpL + t * 512 + TOT);
      short8 bl = *(const short8*)(wpL + t * 512 + 2 * TOT);
      MFMA6(ah, am, al, bh, bm, bl, accL[t]);
      short8 ch = *(const short8*)(wpR + t * 512);
      short8 cm = *(const short8*)(wpR + t * 512 + TOT);
      short8 cl = *(const short8*)(wpR + t * 512 + 2 * TOT);
      MFMA6(ah, am, al, ch, cm, cl, accR[t]);
    }
  }

  float prA[4] = {0.f, 0.f, 0.f, 0.f};
  float prB[4] = {0.f, 0.f, 0.f, 0.f};
  #pragma unroll
  for (int t = 0; t < NT; t++) {
    float bvA = b1a[t * 16 + ln16], wvA = w2a[t * 16 + ln16];
    float bvB = b1b[t * 16 + ln16], wvB = w2b[t * 16 + ln16];
    #pragma unroll
    for (int r = 0; r < 4; r++) {
      prA[r] += fmaxf(accL[t][r] + bvA, 0.f) * wvA;
      prB[r] += fmaxf(accR[t][r] + bvB, 0.f) * wvB;
    }
  }
  #pragma unroll
  for (int o = 1; o < 16; o <<= 1)
    #pragma unroll
    for (int r = 0; r < 4; r++) {
      prA[r] += __shfl_xor(prA[r], o);
      prB[r] += __shfl_xor(prB[r], o);
    }
  if (ln16 == 0) {
    const float bb2a = b2a[0], bb2b = b2b[0];
    const int rbase = blockIdx.x * 64 + wave * 16 + quad * 4;
    #pragma unroll
    for (int r = 0; r < 4; r++) {
      int rr = rbase + r;
      if (rr < nrows) {
        out[(size_t)rr * 2 + 0] = prA[r] + bb2a;
        out[(size_t)rr * 2 + 1] = prB[r] + bb2b;
      }
    }
  }
}

// ---------- fused GAT layer -------------------------------------------------
// Wave per dst row; each 16-lane QUARTER processes its own edge stream.
// Edge loop software-pipelined DEPTH 2: for the typical quarter (cnt<=2) the
// whole stream is issued before the first process step -> gather latency
// overlaps the row prologue instead of stalling per-iteration.
template <int H>
__global__ __launch_bounds__(256) void gat_fused_kernel(
    const float* __restrict__ xl, const float* __restrict__ xr,
    const int* __restrict__ csr_src, const int* __restrict__ row_end,
    const int* __restrict__ deg, const float* __restrict__ att,
    const float* __restrict__ res, const float* __restrict__ g,
    const float* __restrict__ b, float* __restrict__ y, int n,
    float resScale, int doRelu) {
  int row = blockIdx.x * 4 + (threadIdx.x >> 6);
  if (row >= n) return;
  int l = threadIdx.x & 63;
  int q = l >> 4;
  int ln = l & 15;
  int cb = ln * 32;  // byte offset of lane's 8-channel chunk
  int end = row_end[row];
  int dg = deg[row];
  int start = end - dg;
  int cnt = (dg - q + 3) >> 2;  // edges for this quarter (dg >= 1 always)

  const char* xrb = (const char*)xr + (size_t)row * 512 + cb;
  f4v xr0 = __builtin_nontemporal_load((const f4v*)xrb);
  f4v xr1 = __builtin_nontemporal_load((const f4v*)(xrb + 16));
  f4v av0 = *(const f4v*)((const char*)att + cb);
  f4v av1 = *(const f4v*)((const char*)att + cb + 16);

  float s = 0.f;
  float ac[8] = {0.f, 0.f, 0.f, 0.f, 0.f, 0.f, 0.f, 0.f};

  int idx = start + q;
  f4v pa0 = {0.f, 0.f, 0.f, 0.f}, pa1 = pa0;  // edge i   (front of pipe)
  f4v pb0 = pa0, pb1 = pa0;                   // edge i+1
  if (cnt > 0) {
    const char* p = (const char*)xl + (size_t)csr_src[idx] * 512 + cb;
    pa0 = *(const f4v*)p;
    pa1 = *(const f4v*)(p + 16);
  }
  if (cnt > 1) {
    const char* p = (const char*)xl + (size_t)csr_src[idx + 4] * 512 + cb;
    pb0 = *(const f4v*)p;
    pb1 = *(const f4v*)(p + 16);
  }
  for (int i = 0; i < cnt; i++) {
    f4v x0 = pa0, x1 = pa1;
    pa0 = pb0; pa1 = pb1;
    if (i + 2 < cnt) {
      const char* p = (const char*)xl + (size_t)csr_src[idx + 8] * 512 + cb;
      pb0 = *(const f4v*)p;
      pb1 = *(const f4v*)(p + 16);
    }
    idx += 4;
    float p0;
    {
      float t0 = x0.x + xr0.x, t1 = x0.y + xr0.y;
      float t2 = x0.z + xr0.z, t3 = x0.w + xr0.w;
      float t4 = x1.x + xr1.x, t5 = x1.y + xr1.y;
      float t6 = x1.z + xr1.z, t7 = x1.w + xr1.w;
      float v0 = fmaxf(t0, NEG_SLOPE * t0), v1 = fmaxf(t1, NEG_SLOPE * t1);
      float v2 = fmaxf(t2, NEG_SLOPE * t2), v3 = fmaxf(t3, NEG_SLOPE * t3);
      float v4 = fmaxf(t4, NEG_SLOPE * t4), v5 = fmaxf(t5, NEG_SLOPE * t5);
      float v6 = fmaxf(t6, NEG_SLOPE * t6), v7 = fmaxf(t7, NEG_SLOPE * t7);
      p0 = v0 * av0.x + v1 * av0.y + v2 * av0.z + v3 * av0.w +
           v4 * av1.x + v5 * av1.y + v6 * av1.z + v7 * av1.w;
    }
    if constexpr (H == 1) {  // logit over 128 ch = 16 lanes
      #pragma unroll
      for (int o = 1; o < 16; o <<= 1) p0 += __shfl_xor(p0, o);
    } else {                 // H=4: head = 32 ch = 4 lanes
      p0 += __shfl_xor(p0, 1);
      p0 += __shfl_xor(p0, 2);
    }
    float e = __expf(p0);
    s += e;
    ac[0] += e * x0.x; ac[1] += e * x0.y; ac[2] += e * x0.z; ac[3] += e * x0.w;
    ac[4] += e * x1.x; ac[5] += e * x1.y; ac[6] += e * x1.z; ac[7] += e * x1.w;
  }
  // combine the four quarter streams (plain sums)
  s += __shfl_xor(s, 16);
  s += __shfl_xor(s, 32);
  #pragma unroll
  for (int j = 0; j < 8; j++) {
    ac[j] += __shfl_xor(ac[j], 16);
    ac[j] += __shfl_xor(ac[j], 32);
  }

  float inv = 1.f / s;
  float ov[8];
  #pragma unroll
  for (int j = 0; j < 8; j++) ov[j] = ac[j] * inv;

  // LayerNorm over 128 (16 lanes of a quarter cover all channels)
  float sum = 0.f, sq = 0.f;
  #pragma unroll
  for (int j = 0; j < 8; j++) { sum += ov[j]; sq += ov[j] * ov[j]; }
  #pragma unroll
  for (int o = 1; o < 16; o <<= 1) {
    sum += __shfl_xor(sum, o);
    sq += __shfl_xor(sq, o);
  }
  float mean = sum * (1.f / 128.f);
  float var = sq * (1.f / 128.f) - mean * mean;
  float rstd = rsqrtf(var + 1e-5f);

  f4v gv0 = *(const f4v*)((const char*)g + cb);
  f4v gv1 = *(const f4v*)((const char*)g + cb + 16);
  f4v bv0 = *(const f4v*)((const char*)b + cb);
  f4v bv1 = *(const f4v*)((const char*)b + cb + 16);
  float gg[8] = {gv0.x, gv0.y, gv0.z, gv0.w, gv1.x, gv1.y, gv1.z, gv1.w};
  float bb[8] = {bv0.x, bv0.y, bv0.z, bv0.w, bv1.x, bv1.y, bv1.z, bv1.w};
  float rv[8];
  #pragma unroll
  for (int j = 0; j < 8; j++) rv[j] = (ov[j] - mean) * rstd * gg[j] + bb[j];
  if (res) {
    const char* rb = (const char*)res + (size_t)row * 512 + cb;
    f4v r0 = __builtin_nontemporal_load((const f4v*)rb);
    f4v r1 = __builtin_nontemporal_load((const f4v*)(rb + 16));
    rv[0] += resScale * r0.x; rv[1] += resScale * r0.y;
    rv[2] += resScale * r0.z; rv[3] += resScale * r0.w;
    rv[4] += resScale * r1.x; rv[5] += resScale * r1.y;
    rv[6] += resScale * r1.z; rv[7] += resScale * r1.w;
  }
  if (doRelu) {
    #pragma unroll
    for (int j = 0; j < 8; j++) rv[j] = fmaxf(rv[j], 0.f);
  }
  if (q == 0) {
    char* yb = (char*)y + (size_t)row * 512 + cb;
    *(f4v*)yb = (f4v){rv[0], rv[1], rv[2], rv[3]};
    *(f4v*)(yb + 16) = (f4v){rv[4], rv[5], rv[6], rv[7]};
  }
}

// ---------- launch ----------
extern "C" void kernel_launch(void* const* d_in, const int* in_sizes, int n_in,
                              void* d_out, int out_size, void* d_ws,
                              size_t ws_size, hipStream_t stream) {
  const float* x       = (const float*)d_in[0];
  const int*   ei      = (const int*)d_in[1];
  const float* ln_in_g = (const float*)d_in[2];
  const float* ln_in_b = (const float*)d_in[3];
  const float* w_l1    = (const float*)d_in[4];
  const float* w_r1    = (const float*)d_in[5];
  const float* att1    = (const float*)d_in[6];
  const float* ln1_g   = (const float*)d_in[7];
  const float* ln1_b   = (const float*)d_in[8];
  const float* w_l2    = (const float*)d_in[9];
  const float* w_r2    = (const float*)d_in[10];
  const float* att2    = (const float*)d_in[11];
  const float* ln2_g   = (const float*)d_in[12];
  const float* ln2_b   = (const float*)d_in[13];
  const float* w_l3    = (const float*)d_in[14];
  const float* w_r3    = (const float*)d_in[15];
  const float* att3    = (const float*)d_in[16];
  const float* ln3_g   = (const float*)d_in[17];
  const float* ln3_b   = (const float*)d_in[18];
  const float* rtt_w1  = (const float*)d_in[19];
  const float* rtt_b1  = (const float*)d_in[20];
  const float* rtt_w2  = (const float*)d_in[21];
  const float* rtt_b2  = (const float*)d_in[22];
  const float* ret_w1  = (const float*)d_in[23];
  const float* ret_b1  = (const float*)d_in[24];
  const float* ret_w2  = (const float*)d_in[25];
  const float* ret_b2  = (const float*)d_in[26];

  const int N = in_sizes[0] / 64;
  const int E = in_sizes[1] / 2;
  const int ET = E + N;
  const size_t NF = (size_t)N * 128;

  float* A = (float*)d_ws;            // node features h / residual
  float* B = A + NF;                  // xl
  float* C = B + NF;                  // xr
  int* deg     = (int*)(C + NF);      // N
  int* rowcur  = deg + N;             // N (row_end after scatter)
  int* incl    = rowcur + N;          // N
  int* bsums   = incl + N;            // 1024
  int* csr_src = bsums + 1024;        // ET
  short* wf = (short*)(((uintptr_t)(csr_src + ET) + 63) & ~(uintptr_t)63);

  float* out = (float*)d_out;

  // segments: wl1, wr1, wl2, wr2, wl3, wr3, rtt_w1, ret_w1
  const int segsz[8] = {64 * 128, 64 * 128, 128 * 128, 128 * 128,
                        128 * 128, 128 * 128, 128 * 64, 128 * 64};
  PrepArgs pa;
  pa.w[0] = w_l1; pa.w[1] = w_r1; pa.w[2] = w_l2; pa.w[3] = w_r2;
  pa.w[4] = w_l3; pa.w[5] = w_r3; pa.w[6] = rtt_w1; pa.w[7] = ret_w1;
  pa.fout[0] = 128; pa.fout[1] = 128; pa.fout[2] = 128; pa.fout[3] = 128;
  pa.fout[4] = 128; pa.fout[5] = 128; pa.fout[6] = 64; pa.fout[7] = 64;
  int acc = 0;
  short* op = wf;
  for (int s = 0; s < 8; s++) {
    pa.cum[s] = acc;
    pa.o[s] = op;
    op += 3 * segsz[s];  // h + m + l planes
    acc += segsz[s];
  }
  pa.cum[8] = acc;

  const int rowBlocks  = (N + 3) / 4;
  const int mmBlocks   = (N + 63) / 64;    // head kernel: 64 rows/block
  const int mmBlocks2  = (N + 127) / 128;  // 32-row-wave GEMMs: 128 rows/block
  const int NB = (N + 1023) / 1024;
  dim3 lrGrid(mmBlocks2, 2);

  // ---- W fragment prep ----
  prep_w_kernel<<<(acc + 255) / 256, 256, 0, stream>>>(pa);

  // ---- CSR build (by dst) ----
  fill_ones_kernel<<<(N + 255) / 256, 256, 0, stream>>>(deg, N);
  degree_count_kernel<<<(E + 255) / 256, 256, 0, stream>>>(ei, E, deg);
  scan1_kernel<<<NB, 1024, 0, stream>>>(deg, N, incl, bsums);
  scan2_kernel<<<1, 1024, 0, stream>>>(bsums, NB);
  scan3_kernel<<<NB, 1024, 0, stream>>>(incl, deg, bsums, N, rowcur);
  scatter_kernel<<<(ET + 255) / 256, 256, 0, stream>>>(ei, E, ET, rowcur, csr_src);

  // ---- layer 0: fused LN64 + GEMM 64->128 (y-split L/R), 4 heads, relu ----
  mfma_gemm_ln_kernel<<<lrGrid, 256, 0, stream>>>(
      x, ln_in_g, ln_in_b, pa.o[0], pa.o[1], B, C, N);
  gat_fused_kernel<4><<<rowBlocks, 256, 0, stream>>>(
      B, C, csr_src, rowcur, deg, att1, nullptr, ln1_g, ln1_b, A, N, 0.f, 1);

  // ---- layer 1: 128 -> 128 (y-split L/R), 4 heads, residual 0.1, relu ----
  mfma_gemm_lr_kernel<<<lrGrid, 256, 0, stream>>>(A, pa.o[2], pa.o[3], B, C, N);
  gat_fused_kernel<4><<<rowBlocks, 256, 0, stream>>>(
      B, C, csr_src, rowcur, deg, att2, A, ln2_g, ln2_b, A, N, 0.1f, 1);

  // ---- layer 2: 128 -> 128 (y-split L/R), 1 head, residual 0.1, no relu ----
  mfma_gemm_lr_kernel<<<lrGrid, 256, 0, stream>>>(A, pa.o[4], pa.o[5], B, C, N);
  gat_fused_kernel<1><<<rowBlocks, 256, 0, stream>>>(
      B, C, csr_src, rowcur, deg, att3, A, ln3_g, ln3_b, A, N, 0.1f, 0);

  // ---- prediction heads: both GEMMs + relu + final dots in one dispatch ----
  mfma_head_lr_kernel<<<mmBlocks, 256, 0, stream>>>(
      A, pa.o[6], rtt_b1, rtt_w2, rtt_b2, pa.o[7], ret_b1, ret_w2, ret_b2,
      out, N);
}

// Round 15
// 641.379 us; speedup vs baseline: 1.1633x; 1.0195x over previous
//
#include <hip/hip_runtime.h>
#include <hip/hip_bf16.h>
#include <cstdint>
#include <cstddef>

#define NEG_SLOPE 0.2f

typedef float f4v __attribute__((ext_vector_type(4)));
typedef short short8 __attribute__((ext_vector_type(8)));
typedef float f32x4 __attribute__((ext_vector_type(4)));

// Explicit round-to-nearest-even fp32 -> bf16 (integer form; r12 evidence:
// __float2bfloat16 truncates on this ROCm -> biased residual -> e-3 scatter).
__device__ __forceinline__ short rne_bf16(float v) {
  unsigned u = __builtin_bit_cast(unsigned, v);
  u += 0x7FFFu + ((u >> 16) & 1u);
  return (short)(u >> 16);
}
__device__ __forceinline__ float bf16_to_f(short h) {
  unsigned u = ((unsigned)(unsigned short)h) << 16;
  return __builtin_bit_cast(float, u);
}
// fp32 -> 3x bf16, RNE at each level. Residual <= 2^-27|v|, unbiased.
__device__ __forceinline__ void cvt3(float v, short& h, short& m, short& l) {
  h = rne_bf16(v);
  float r1 = v - bf16_to_f(h);
  m = rne_bf16(r1);
  float r2 = r1 - bf16_to_f(m);
  l = rne_bf16(r2);
}

// ---------- CSR build ----------

__global__ __launch_bounds__(256) void fill_ones_kernel(int* __restrict__ p, int n) {
  int i = blockIdx.x * 256 + threadIdx.x;
  if (i < n) p[i] = 1;  // self-loop contributes degree 1
}

__global__ __launch_bounds__(256) void degree_count_kernel(
    const int* __restrict__ ei, int E, int* __restrict__ deg) {
  int e = blockIdx.x * 256 + threadIdx.x;
  if (e < E) atomicAdd(&deg[ei[E + e]], 1);
}

__global__ __launch_bounds__(1024) void scan1_kernel(
    const int* __restrict__ deg, int n, int* __restrict__ incl,
    int* __restrict__ blocksums) {
  __shared__ int sm[1024];
  int t = threadIdx.x;
  int i = blockIdx.x * 1024 + t;
  sm[t] = (i < n) ? deg[i] : 0;
  __syncthreads();
  #pragma unroll
  for (int o = 1; o < 1024; o <<= 1) {
    int a = (t >= o) ? sm[t - o] : 0;
    __syncthreads();
    sm[t] += a;
    __syncthreads();
  }
  if (i < n) incl[i] = sm[t];
  if (t == 1023) blocksums[blockIdx.x] = sm[t];
}

// scan3 with scan2 folded in: every block locally prefix-sums the (<=1024)
// block sums (NB ~ 98 -> negligible), then writes exclusive row starts.
__global__ __launch_bounds__(1024) void scan23_kernel(
    const int* __restrict__ incl, const int* __restrict__ deg,
    const int* __restrict__ bs, int nb, int n, int* __restrict__ rowcur) {
  int i = blockIdx.x * 1024 + threadIdx.x;
  if (i >= n) return;
  int off = 0;
  for (int j = 0; j < (int)blockIdx.x; j++) off += bs[j];  // nb<=98, L2-hot
  rowcur[i] = incl[i] - deg[i] + off;
}

__global__ __launch_bounds__(256) void scatter_kernel(
    const int* __restrict__ ei, int E, int ET, int* __restrict__ rowcur,
    int* __restrict__ csr_src) {
  int e = blockIdx.x * 256 + threadIdx.x;
  if (e >= ET) return;
  int s, d;
  if (e < E) { s = ei[e]; d = ei[E + e]; }
  else       { s = e - E; d = s; }
  int pos = atomicAdd(&rowcur[d], 1);
  csr_src[pos] = s;
}

// ---------- W -> MFMA B-fragment layout (triple bf16 planes) ----------
struct PrepArgs {
  const float* w[8];
  short* o[8];
  int fout[8];
  int cum[9];
};

__global__ __launch_bounds__(256) void prep_w_kernel(PrepArgs pa) {
  int i = blockIdx.x * 256 + threadIdx.x;
  if (i >= pa.cum[8]) return;
  int s = 0;
  while (i >= pa.cum[s + 1]) s++;
  int li = i - pa.cum[s];
  int FOUT = pa.fout[s];
  int NT = FOUT >> 4;
  int sz = pa.cum[s + 1] - pa.cum[s];
  int c = li / (NT * 512);
  int r1 = li % (NT * 512);
  int t = r1 >> 9;
  int e = r1 & 511;
  int lane = e >> 3, j = e & 7;
  int k = c * 32 + (lane >> 4) * 8 + j;
  int n = t * 16 + (lane & 15);
  float v = pa.w[s][k * FOUT + n];
  short h, m, l;
  cvt3(v, h, m, l);
  pa.o[s][li] = h;
  pa.o[s][li + sz] = m;
  pa.o[s][li + 2 * sz] = l;
}

// 6-term triple-split MFMA accumulate for one tile
#define MFMA6(ah, am, al, bh, bm, bl, acc)                                   \
  acc = __builtin_amdgcn_mfma_f32_16x16x32_bf16(ah, bh, acc, 0, 0, 0);      \
  acc = __builtin_amdgcn_mfma_f32_16x16x32_bf16(ah, bm, acc, 0, 0, 0);      \
  acc = __builtin_amdgcn_mfma_f32_16x16x32_bf16(am, bh, acc, 0, 0, 0);      \
  acc = __builtin_amdgcn_mfma_f32_16x16x32_bf16(ah, bl, acc, 0, 0, 0);      \
  acc = __builtin_amdgcn_mfma_f32_16x16x32_bf16(am, bm, acc, 0, 0, 0);      \
  acc = __builtin_amdgcn_mfma_f32_16x16x32_bf16(al, bh, acc, 0, 0, 0);

// ---------- layer-0 GEMM: fused LN64, 32 rows/wave, y-split L/R ------------
__global__ __launch_bounds__(256, 2) void mfma_gemm_ln_kernel(
    const float* __restrict__ X, const float* __restrict__ lng,
    const float* __restrict__ lnb, const short* __restrict__ WfL,
    const short* __restrict__ WfR, float* __restrict__ YL,
    float* __restrict__ YR, int nrows) {
  constexpr int NT = 8, TOT = 2 * NT * 512;
  const short* Wf = blockIdx.y ? WfR : WfL;
  float* Y = blockIdx.y ? YR : YL;
  const int wave = threadIdx.x >> 6, lane = threadIdx.x & 63;
  const int quad = lane >> 4, ln16 = lane & 15;
  const int rb = blockIdx.x * 128 + wave * 32;
  int r0 = rb + ln16;      int rA0 = r0 < nrows ? r0 : nrows - 1;
  int r1 = rb + 16 + ln16; int rA1 = r1 < nrows ? r1 : nrows - 1;
  const float* xp0 = X + (size_t)rA0 * 64 + quad * 8;
  const float* xp1 = X + (size_t)rA1 * 64 + quad * 8;

  float av0[16], av1[16];
  *(float4*)&av0[0]  = *(const float4*)(xp0);
  *(float4*)&av0[4]  = *(const float4*)(xp0 + 4);
  *(float4*)&av0[8]  = *(const float4*)(xp0 + 32);
  *(float4*)&av0[12] = *(const float4*)(xp0 + 36);
  *(float4*)&av1[0]  = *(const float4*)(xp1);
  *(float4*)&av1[4]  = *(const float4*)(xp1 + 4);
  *(float4*)&av1[8]  = *(const float4*)(xp1 + 32);
  *(float4*)&av1[12] = *(const float4*)(xp1 + 36);

  float s0 = 0.f, q0 = 0.f, s1 = 0.f, q1 = 0.f;
  #pragma unroll
  for (int j = 0; j < 16; j++) {
    s0 += av0[j]; q0 += av0[j] * av0[j];
    s1 += av1[j]; q1 += av1[j] * av1[j];
  }
  s0 += __shfl_xor(s0, 16); s0 += __shfl_xor(s0, 32);
  q0 += __shfl_xor(q0, 16); q0 += __shfl_xor(q0, 32);
  s1 += __shfl_xor(s1, 16); s1 += __shfl_xor(s1, 32);
  q1 += __shfl_xor(q1, 16); q1 += __shfl_xor(q1, 32);
  float mean0 = s0 * (1.f / 64.f);
  float rstd0 = rsqrtf(q0 * (1.f / 64.f) - mean0 * mean0 + 1e-5f);
  float mean1 = s1 * (1.f / 64.f);
  float rstd1 = rsqrtf(q1 * (1.f / 64.f) - mean1 * mean1 + 1e-5f);

  f32x4 acc0[NT], acc1[NT];
  #pragma unroll
  for (int t = 0; t < NT; t++) {
    acc0[t] = (f32x4){0.f, 0.f, 0.f, 0.f};
    acc1[t] = (f32x4){0.f, 0.f, 0.f, 0.f};
  }

  #pragma unroll
  for (int c = 0; c < 2; c++) {
    float4 gv0 = *(const float4*)&lng[quad * 8 + c * 32];
    float4 gv1 = *(const float4*)&lng[quad * 8 + c * 32 + 4];
    float4 bv0 = *(const float4*)&lnb[quad * 8 + c * 32];
    float4 bv1 = *(const float4*)&lnb[quad * 8 + c * 32 + 4];
    float gg[8] = {gv0.x, gv0.y, gv0.z, gv0.w, gv1.x, gv1.y, gv1.z, gv1.w};
    float bb[8] = {bv0.x, bv0.y, bv0.z, bv0.w, bv1.x, bv1.y, bv1.z, bv1.w};
    short8 a0h, a0m, a0l, a1h, a1m, a1l;
    #pragma unroll
    for (int j = 0; j < 8; j++) {
      float v0 = (av0[c * 8 + j] - mean0) * rstd0 * gg[j] + bb[j];
      float v1 = (av1[c * 8 + j] - mean1) * rstd1 * gg[j] + bb[j];
      short h, m, l;
      cvt3(v0, h, m, l); a0h[j] = h; a0m[j] = m; a0l[j] = l;
      cvt3(v1, h, m, l); a1h[j] = h; a1m[j] = m; a1l[j] = l;
    }
    const short* wp = Wf + c * NT * 512 + lane * 8;
    #pragma unroll
    for (int t = 0; t < NT; t++) {
      short8 bh = *(const short8*)(wp + t * 512);
      short8 bm = *(const short8*)(wp + t * 512 + TOT);
      short8 bl = *(const short8*)(wp + t * 512 + 2 * TOT);
      MFMA6(a0h, a0m, a0l, bh, bm, bl, acc0[t]);
      MFMA6(a1h, a1m, a1l, bh, bm, bl, acc1[t]);
    }
  }

  const int rbase = rb + quad * 4;
  #pragma unroll
  for (int t = 0; t < NT; t++)
    #pragma unroll
    for (int r = 0; r < 4; r++) {
      int ra = rbase + r, rbs = rbase + 16 + r;
      if (ra < nrows) Y[(size_t)ra * 128 + t * 16 + ln16] = acc0[t][r];
      if (rbs < nrows) Y[(size_t)rbs * 128 + t * 16 + ln16] = acc1[t][r];
    }
}

// ---------- generic MFMA GEMM: FIN=128, 32 rows/wave, y-split L/R ----------
__global__ __launch_bounds__(256, 2) void mfma_gemm_lr_kernel(
    const float* __restrict__ X, const short* __restrict__ WfL,
    const short* __restrict__ WfR, float* __restrict__ YL,
    float* __restrict__ YR, int nrows) {
  constexpr int NC = 4, NT = 8, TOT = NC * NT * 512;
  const short* Wf = blockIdx.y ? WfR : WfL;
  float* Y = blockIdx.y ? YR : YL;
  const int wave = threadIdx.x >> 6, lane = threadIdx.x & 63;
  const int quad = lane >> 4, ln16 = lane & 15;
  const int rb = blockIdx.x * 128 + wave * 32;
  int r0 = rb + ln16;      int rA0 = r0 < nrows ? r0 : nrows - 1;
  int r1 = rb + 16 + ln16; int rA1 = r1 < nrows ? r1 : nrows - 1;
  const float* xp0 = X + (size_t)rA0 * 128 + quad * 8;
  const float* xp1 = X + (size_t)rA1 * 128 + quad * 8;

  f32x4 acc0[NT], acc1[NT];
  #pragma unroll
  for (int t = 0; t < NT; t++) {
    acc0[t] = (f32x4){0.f, 0.f, 0.f, 0.f};
    acc1[t] = (f32x4){0.f, 0.f, 0.f, 0.f};
  }

  #pragma unroll
  for (int c = 0; c < NC; c++) {
    float4 x00 = *(const float4*)(xp0 + c * 32);
    float4 x01 = *(const float4*)(xp0 + c * 32 + 4);
    float4 x10 = *(const float4*)(xp1 + c * 32);
    float4 x11 = *(const float4*)(xp1 + c * 32 + 4);
    float a0[8] = {x00.x, x00.y, x00.z, x00.w, x01.x, x01.y, x01.z, x01.w};
    float a1[8] = {x10.x, x10.y, x10.z, x10.w, x11.x, x11.y, x11.z, x11.w};
    short8 a0h, a0m, a0l, a1h, a1m, a1l;
    #pragma unroll
    for (int j = 0; j < 8; j++) {
      short h, m, l;
      cvt3(a0[j], h, m, l); a0h[j] = h; a0m[j] = m; a0l[j] = l;
      cvt3(a1[j], h, m, l); a1h[j] = h; a1m[j] = m; a1l[j] = l;
    }
    const short* wp = Wf + c * NT * 512 + lane * 8;
    #pragma unroll
    for (int t = 0; t < NT; t++) {
      short8 bh = *(const short8*)(wp + t * 512);
      short8 bm = *(const short8*)(wp + t * 512 + TOT);
      short8 bl = *(const short8*)(wp + t * 512 + 2 * TOT);
      MFMA6(a0h, a0m, a0l, bh, bm, bl, acc0[t]);
      MFMA6(a1h, a1m, a1l, bh, bm, bl, acc1[t]);
    }
  }

  const int rbase = rb + quad * 4;
  #pragma unroll
  for (int t = 0; t < NT; t++)
    #pragma unroll
    for (int r = 0; r < 4; r++) {
      int ra = rbase + r, rbs = rbase + 16 + r;
      if (ra < nrows) Y[(size_t)ra * 128 + t * 16 + ln16] = acc0[t][r];
      if (rbs < nrows) Y[(size_t)rbs * 128 + t * 16 + ln16] = acc1[t][r];
    }
}

// ---------- head GEMMs fused with final dots: out[row,0..1] in one block ---
__global__ __launch_bounds__(256, 2) void mfma_head_lr_kernel(
    const float* __restrict__ X, const short* __restrict__ Wf1,
    const float* __restrict__ b1a, const float* __restrict__ w2a,
    const float* __restrict__ b2a, const short* __restrict__ Wf2,
    const float* __restrict__ b1b, const float* __restrict__ w2b,
    const float* __restrict__ b2b, float* __restrict__ out, int nrows) {
  constexpr int NC = 4, NT = 4, TOT = NC * NT * 512;
  const int wave = threadIdx.x >> 6, lane = threadIdx.x & 63;
  const int quad = lane >> 4, ln16 = lane & 15;
  int rowA = blockIdx.x * 64 + wave * 16 + ln16;
  int rA = rowA < nrows ? rowA : nrows - 1;
  const float* xp = X + (size_t)rA * 128 + quad * 8;

  f32x4 accL[NT], accR[NT];
  #pragma unroll
  for (int t = 0; t < NT; t++) {
    accL[t] = (f32x4){0.f, 0.f, 0.f, 0.f};
    accR[t] = (f32x4){0.f, 0.f, 0.f, 0.f};
  }

  #pragma unroll
  for (int c = 0; c < NC; c++) {
    float4 a0 = *(const float4*)(xp + c * 32);
    float4 a1 = *(const float4*)(xp + c * 32 + 4);
    float av[8] = {a0.x, a0.y, a0.z, a0.w, a1.x, a1.y, a1.z, a1.w};
    short8 ah, am, al;
    #pragma unroll
    for (int j = 0; j < 8; j++) {
      short h, m, l;
      cvt3(av[j], h, m, l);
      ah[j] = h; am[j] = m; al[j] = l;
    }
    const short* wpL = Wf1 + c * NT * 512 + lane * 8;
    const short* wpR = Wf2 + c * NT * 512 + lane * 8;
    #pragma unroll
    for (int t = 0; t < NT; t++) {
      short8 bh = *(const short8*)(wpL + t * 512);
      short8 bm = *(const short8*)(wpL + t * 512 + TOT);
      short8 bl = *(const short8*)(wpL + t * 512 + 2 * TOT);
      MFMA6(ah, am, al, bh, bm, bl, accL[t]);
      short8 ch = *(const short8*)(wpR + t * 512);
      short8 cm = *(const short8*)(wpR + t * 512 + TOT);
      short8 cl = *(const short8*)(wpR + t * 512 + 2 * TOT);
      MFMA6(ah, am, al, ch, cm, cl, accR[t]);
    }
  }

  float prA[4] = {0.f, 0.f, 0.f, 0.f};
  float prB[4] = {0.f, 0.f, 0.f, 0.f};
  #pragma unroll
  for (int t = 0; t < NT; t++) {
    float bvA = b1a[t * 16 + ln16], wvA = w2a[t * 16 + ln16];
    float bvB = b1b[t * 16 + ln16], wvB = w2b[t * 16 + ln16];
    #pragma unroll
    for (int r = 0; r < 4; r++) {
      prA[r] += fmaxf(accL[t][r] + bvA, 0.f) * wvA;
      prB[r] += fmaxf(accR[t][r] + bvB, 0.f) * wvB;
    }
  }
  #pragma unroll
  for (int o = 1; o < 16; o <<= 1)
    #pragma unroll
    for (int r = 0; r < 4; r++) {
      prA[r] += __shfl_xor(prA[r], o);
      prB[r] += __shfl_xor(prB[r], o);
    }
  if (ln16 == 0) {
    const float bb2a = b2a[0], bb2b = b2b[0];
    const int rbase = blockIdx.x * 64 + wave * 16 + quad * 4;
    #pragma unroll
    for (int r = 0; r < 4; r++) {
      int rr = rbase + r;
      if (rr < nrows) {
        out[(size_t)rr * 2 + 0] = prA[r] + bb2a;
        out[(size_t)rr * 2 + 1] = prB[r] + bb2b;
      }
    }
  }
}

// ---------- fused GAT layer -------------------------------------------------
// ONE WAVE PER BLOCK (64 threads): waves retire independently -> no
// intra-block coupling on skewed degrees. Each 16-lane quarter processes its
// own edge stream, depth-2 pipelined. y stored nontemporal so the streamed
// output doesn't evict the L3-resident xl gather working set.
template <int H>
__global__ __launch_bounds__(64) void gat_fused_kernel(
    const float* __restrict__ xl, const float* __restrict__ xr,
    const int* __restrict__ csr_src, const int* __restrict__ row_end,
    const int* __restrict__ deg, const float* __restrict__ att,
    const float* __restrict__ res, const float* __restrict__ g,
    const float* __restrict__ b, float* __restrict__ y, int n,
    float resScale, int doRelu) {
  int row = blockIdx.x;
  if (row >= n) return;
  int l = threadIdx.x & 63;
  int q = l >> 4;
  int ln = l & 15;
  int cb = ln * 32;  // byte offset of lane's 8-channel chunk
  int end = row_end[row];
  int dg = deg[row];
  int start = end - dg;
  int cnt = (dg - q + 3) >> 2;  // edges for this quarter (dg >= 1 always)

  const char* xrb = (const char*)xr + (size_t)row * 512 + cb;
  f4v xr0 = __builtin_nontemporal_load((const f4v*)xrb);
  f4v xr1 = __builtin_nontemporal_load((const f4v*)(xrb + 16));
  f4v av0 = *(const f4v*)((const char*)att + cb);
  f4v av1 = *(const f4v*)((const char*)att + cb + 16);

  float s = 0.f;
  float ac[8] = {0.f, 0.f, 0.f, 0.f, 0.f, 0.f, 0.f, 0.f};

  int idx = start + q;
  f4v pa0 = {0.f, 0.f, 0.f, 0.f}, pa1 = pa0;  // edge i   (front of pipe)
  f4v pb0 = pa0, pb1 = pa0;                   // edge i+1
  if (cnt > 0) {
    const char* p = (const char*)xl + (size_t)csr_src[idx] * 512 + cb;
    pa0 = *(const f4v*)p;
    pa1 = *(const f4v*)(p + 16);
  }
  if (cnt > 1) {
    const char* p = (const char*)xl + (size_t)csr_src[idx + 4] * 512 + cb;
    pb0 = *(const f4v*)p;
    pb1 = *(const f4v*)(p + 16);
  }
  for (int i = 0; i < cnt; i++) {
    f4v x0 = pa0, x1 = pa1;
    pa0 = pb0; pa1 = pb1;
    if (i + 2 < cnt) {
      const char* p = (const char*)xl + (size_t)csr_src[idx + 8] * 512 + cb;
      pb0 = *(const f4v*)p;
      pb1 = *(const f4v*)(p + 16);
    }
    idx += 4;
    float p0;
    {
      float t0 = x0.x + xr0.x, t1 = x0.y + xr0.y;
      float t2 = x0.z + xr0.z, t3 = x0.w + xr0.w;
      float t4 = x1.x + xr1.x, t5 = x1.y + xr1.y;
      float t6 = x1.z + xr1.z, t7 = x1.w + xr1.w;
      float v0 = fmaxf(t0, NEG_SLOPE * t0), v1 = fmaxf(t1, NEG_SLOPE * t1);
      float v2 = fmaxf(t2, NEG_SLOPE * t2), v3 = fmaxf(t3, NEG_SLOPE * t3);
      float v4 = fmaxf(t4, NEG_SLOPE * t4), v5 = fmaxf(t5, NEG_SLOPE * t5);
      float v6 = fmaxf(t6, NEG_SLOPE * t6), v7 = fmaxf(t7, NEG_SLOPE * t7);
      p0 = v0 * av0.x + v1 * av0.y + v2 * av0.z + v3 * av0.w +
           v4 * av1.x + v5 * av1.y + v6 * av1.z + v7 * av1.w;
    }
    if constexpr (H == 1) {  // logit over 128 ch = 16 lanes
      #pragma unroll
      for (int o = 1; o < 16; o <<= 1) p0 += __shfl_xor(p0, o);
    } else {                 // H=4: head = 32 ch = 4 lanes
      p0 += __shfl_xor(p0, 1);
      p0 += __shfl_xor(p0, 2);
    }
    float e = __expf(p0);
    s += e;
    ac[0] += e * x0.x; ac[1] += e * x0.y; ac[2] += e * x0.z; ac[3] += e * x0.w;
    ac[4] += e * x1.x; ac[5] += e * x1.y; ac[6] += e * x1.z; ac[7] += e * x1.w;
  }
  // combine the four quarter streams (plain sums)
  s += __shfl_xor(s, 16);
  s += __shfl_xor(s, 32);
  #pragma unroll
  for (int j = 0; j < 8; j++) {
    ac[j] += __shfl_xor(ac[j], 16);
    ac[j] += __shfl_xor(ac[j], 32);
  }

  float inv = 1.f / s;
  float ov[8];
  #pragma unroll
  for (int j = 0; j < 8; j++) ov[j] = ac[j] * inv;

  // LayerNorm over 128 (16 lanes of a quarter cover all channels)
  float sum = 0.f, sq = 0.f;
  #pragma unroll
  for (int j = 0; j < 8; j++) { sum += ov[j]; sq += ov[j] * ov[j]; }
  #pragma unroll
  for (int o = 1; o < 16; o <<= 1) {
    sum += __shfl_xor(sum, o);
    sq += __shfl_xor(sq, o);
  }
  float mean = sum * (1.f / 128.f);
  float var = sq * (1.f / 128.f) - mean * mean;
  float rstd = rsqrtf(var + 1e-5f);

  f4v gv0 = *(const f4v*)((const char*)g + cb);
  f4v gv1 = *(const f4v*)((const char*)g + cb + 16);
  f4v bv0 = *(const f4v*)((const char*)b + cb);
  f4v bv1 = *(const f4v*)((const char*)b + cb + 16);
  float gg[8] = {gv0.x, gv0.y, gv0.z, gv0.w, gv1.x, gv1.y, gv1.z, gv1.w};
  float bb[8] = {bv0.x, bv0.y, bv0.z, bv0.w, bv1.x, bv1.y, bv1.z, bv1.w};
  float rv[8];
  #pragma unroll
  for (int j = 0; j < 8; j++) rv[j] = (ov[j] - mean) * rstd * gg[j] + bb[j];
  if (res) {
    const char* rb = (const char*)res + (size_t)row * 512 + cb;
    f4v r0 = __builtin_nontemporal_load((const f4v*)rb);
    f4v r1 = __builtin_nontemporal_load((const f4v*)(rb + 16));
    rv[0] += resScale * r0.x; rv[1] += resScale * r0.y;
    rv[2] += resScale * r0.z; rv[3] += resScale * r0.w;
    rv[4] += resScale * r1.x; rv[5] += resScale * r1.y;
    rv[6] += resScale * r1.z; rv[7] += resScale * r1.w;
  }
  if (doRelu) {
    #pragma unroll
    for (int j = 0; j < 8; j++) rv[j] = fmaxf(rv[j], 0.f);
  }
  if (q == 0) {
    char* yb = (char*)y + (size_t)row * 512 + cb;
    f4v o0 = {rv[0], rv[1], rv[2], rv[3]};
    f4v o1 = {rv[4], rv[5], rv[6], rv[7]};
    __builtin_nontemporal_store(o0, (f4v*)yb);
    __builtin_nontemporal_store(o1, (f4v*)(yb + 16));
  }
}

// ---------- launch ----------
extern "C" void kernel_launch(void* const* d_in, const int* in_sizes, int n_in,
                              void* d_out, int out_size, void* d_ws,
                              size_t ws_size, hipStream_t stream) {
  const float* x       = (const float*)d_in[0];
  const int*   ei      = (const int*)d_in[1];
  const float* ln_in_g = (const float*)d_in[2];
  const float* ln_in_b = (const float*)d_in[3];
  const float* w_l1    = (const float*)d_in[4];
  const float* w_r1    = (const float*)d_in[5];
  const float* att1    = (const float*)d_in[6];
  const float* ln1_g   = (const float*)d_in[7];
  const float* ln1_b   = (const float*)d_in[8];
  const float* w_l2    = (const float*)d_in[9];
  const float* w_r2    = (const float*)d_in[10];
  const float* att2    = (const float*)d_in[11];
  const float* ln2_g   = (const float*)d_in[12];
  const float* ln2_b   = (const float*)d_in[13];
  const float* w_l3    = (const float*)d_in[14];
  const float* w_r3    = (const float*)d_in[15];
  const float* att3    = (const float*)d_in[16];
  const float* ln3_g   = (const float*)d_in[17];
  const float* ln3_b   = (const float*)d_in[18];
  const float* rtt_w1  = (const float*)d_in[19];
  const float* rtt_b1  = (const float*)d_in[20];
  const float* rtt_w2  = (const float*)d_in[21];
  const float* rtt_b2  = (const float*)d_in[22];
  const float* ret_w1  = (const float*)d_in[23];
  const float* ret_b1  = (const float*)d_in[24];
  const float* ret_w2  = (const float*)d_in[25];
  const float* ret_b2  = (const float*)d_in[26];

  const int N = in_sizes[0] / 64;
  const int E = in_sizes[1] / 2;
  const int ET = E + N;
  const size_t NF = (size_t)N * 128;

  float* A = (float*)d_ws;            // node features h / residual
  float* B = A + NF;                  // xl
  float* C = B + NF;                  // xr
  int* deg     = (int*)(C + NF);      // N
  int* rowcur  = deg + N;             // N (row_end after scatter)
  int* incl    = rowcur + N;          // N
  int* bsums   = incl + N;            // 1024
  int* csr_src = bsums + 1024;        // ET
  short* wf = (short*)(((uintptr_t)(csr_src + ET) + 63) & ~(uintptr_t)63);

  float* out = (float*)d_out;

  // segments: wl1, wr1, wl2, wr2, wl3, wr3, rtt_w1, ret_w1
  const int segsz[8] = {64 * 128, 64 * 128, 128 * 128, 128 * 128,
                        128 * 128, 128 * 128, 128 * 64, 128 * 64};
  PrepArgs pa;
  pa.w[0] = w_l1; pa.w[1] = w_r1; pa.w[2] = w_l2; pa.w[3] = w_r2;
  pa.w[4] = w_l3; pa.w[5] = w_r3; pa.w[6] = rtt_w1; pa.w[7] = ret_w1;
  pa.fout[0] = 128; pa.fout[1] = 128; pa.fout[2] = 128; pa.fout[3] = 128;
  pa.fout[4] = 128; pa.fout[5] = 128; pa.fout[6] = 64; pa.fout[7] = 64;
  int acc = 0;
  short* op = wf;
  for (int s = 0; s < 8; s++) {
    pa.cum[s] = acc;
    pa.o[s] = op;
    op += 3 * segsz[s];  // h + m + l planes
    acc += segsz[s];
  }
  pa.cum[8] = acc;

  const int mmBlocks   = (N + 63) / 64;    // head kernel: 64 rows/block
  const int mmBlocks2  = (N + 127) / 128;  // 32-row-wave GEMMs: 128 rows/block
  const int NB = (N + 1023) / 1024;
  dim3 lrGrid(mmBlocks2, 2);

  // ---- W fragment prep ----
  prep_w_kernel<<<(acc + 255) / 256, 256, 0, stream>>>(pa);

  // ---- CSR build (by dst) ----
  fill_ones_kernel<<<(N + 255) / 256, 256, 0, stream>>>(deg, N);
  degree_count_kernel<<<(E + 255) / 256, 256, 0, stream>>>(ei, E, deg);
  scan1_kernel<<<NB, 1024, 0, stream>>>(deg, N, incl, bsums);
  scan23_kernel<<<NB, 1024, 0, stream>>>(incl, deg, bsums, NB, N, rowcur);
  scatter_kernel<<<(ET + 255) / 256, 256, 0, stream>>>(ei, E, ET, rowcur, csr_src);

  // ---- layer 0: fused LN64 + GEMM 64->128 (y-split L/R), 4 heads, relu ----
  mfma_gemm_ln_kernel<<<lrGrid, 256, 0, stream>>>(
      x, ln_in_g, ln_in_b, pa.o[0], pa.o[1], B, C, N);
  gat_fused_kernel<4><<<N, 64, 0, stream>>>(
      B, C, csr_src, rowcur, deg, att1, nullptr, ln1_g, ln1_b, A, N, 0.f, 1);

  // ---- layer 1: 128 -> 128 (y-split L/R), 4 heads, residual 0.1, relu ----
  mfma_gemm_lr_kernel<<<lrGrid, 256, 0, stream>>>(A, pa.o[2], pa.o[3], B, C, N);
  gat_fused_kernel<4><<<N, 64, 0, stream>>>(
      B, C, csr_src, rowcur, deg, att2, A, ln2_g, ln2_b, A, N, 0.1f, 1);

  // ---- layer 2: 128 -> 128 (y-split L/R), 1 head, residual 0.1, no relu ----
  mfma_gemm_lr_kernel<<<lrGrid, 256, 0, stream>>>(A, pa.o[4], pa.o[5], B, C, N);
  gat_fused_kernel<1><<<N, 64, 0, stream>>>(
      B, C, csr_src, rowcur, deg, att3, A, ln3_g, ln3_b, A, N, 0.1f, 0);

  // ---- prediction heads: both GEMMs + relu + final dots in one dispatch ----
  mfma_head_lr_kernel<<<mmBlocks, 256, 0, stream>>>(
      A, pa.o[6], rtt_b1, rtt_w2, rtt_b2, pa.o[7], ret_b1, ret_w2, ret_b2,
      out, N);
}